// Round 37
// baseline (470.013 us; speedup 1.0000x reference)
//
#include <hip/hip_runtime.h>
#include <hip/hip_bf16.h>
#include <math.h>

#define B_ 4
#define N_ 16384
#define M_ 4096
#define K_ 16
#define C_ 128
#define OUT_ 256
#define TPB 256
#define MAX_R 0.3f
#define BIGF 1e9f
#define LN_EPS_F 1e-5f
#define SEPS 1e-6f
#define BM (B_ * M_)

// KNN exactness (r25, FROZEN): d2 = fma(-2,dot,aq+bq), sq=(x²+z²)+y²,
// dot=fma(c2p2,fma(c1p1,c0p0)), dist=sqrt(d2+eps)<=0.3, (dist,idx) stable.
// r36: C LDS-alias (occ 52%, 210us); A grid-limited at 4 blocks/CU (200us,
// LDS-issue floor ~85us). r37: RUNTIME-CHUNKED A — nchunks=32 (chunk 512,
// dynamic LDS 24KB -> 6 blocks/CU, grid 2048) when ws_size permits, else
// fall back to 16 (r36-identical). Merge order invariant to partition.

typedef __attribute__((ext_vector_type(8))) short bf16x8;
typedef __attribute__((ext_vector_type(4))) float f32x4;

__device__ __forceinline__ unsigned short bfu(float f) {
  __hip_bfloat16 h = __float2bfloat16(f);
  return *reinterpret_cast<unsigned short*>(&h);
}
__device__ __forceinline__ float b2f(unsigned short u) {
  unsigned x = ((unsigned)u) << 16;
  return __uint_as_float(x);
}

// ---------------------------------------------------------------------------
// Kernel A: per-(center, chunk) partial top-16, d2-deferred, runtime chunk
// ---------------------------------------------------------------------------
__global__ __launch_bounds__(TPB) void knn_partial_kernel(
    const float* __restrict__ points, const int* __restrict__ cidx,
    float* __restrict__ pvals, int* __restrict__ pidx, int chunkn)
{
#pragma clang fp contract(off)
  extern __shared__ char smem[];
  float4* pts = (float4*)smem;
  unsigned long long* buf = (unsigned long long*)(smem + (size_t)chunkn * 16);

  const int s  = blockIdx.x;
  const int mg = blockIdx.y;
  const int b  = blockIdx.z;
  const int tid = threadIdx.x;

  const int j0 = s * chunkn;
  for (int e = tid; e < chunkn; e += TPB) {
    int j = j0 + e;
    float x = points[(b * N_ + j) * 3 + 0];
    float y = points[(b * N_ + j) * 3 + 1];
    float z = points[(b * N_ + j) * 3 + 2];
    float bq = (x * x + z * z) + y * y;      // einsum SSE2 tree
    pts[e] = make_float4(x, y, z, bq);
  }

  const int m  = mg * TPB + tid;
  const int cm = b * M_ + m;
  const int ci = cidx[cm];
  const float cx = points[(b * N_ + ci) * 3 + 0];
  const float cy = points[(b * N_ + ci) * 3 + 1];
  const float cz = points[(b * N_ + ci) * 3 + 2];
  const float aq = (cx * cx + cz * cz) + cy * cy;   // einsum SSE2 tree
  __syncthreads();

  float v[16];
  int   id[16];
#pragma unroll
  for (int t = 0; t < 16; t++) { v[t] = 3.4e38f; id[t] = 0; }
  float v15q = 0.0905f;
  int cnt = 0;

  for (int e = 0; e < chunkn; e++) {
    float4 p = pts[e];
    float dot = fmaf(cz, p.z, fmaf(cy, p.y, cx * p.x));  // BLAS fma chain
    float d2 = fmaf(-2.0f, dot, aq + p.w);
    if (d2 < v15q) {
      buf[cnt * TPB + tid] =
          ((unsigned long long)__float_as_uint(d2) << 32) | (unsigned)(j0 + e);
      cnt++;
    }
    if (__any(cnt == 8)) {
      for (int ss = 0; ss < 8; ss++) {
        if (ss < cnt) {
          unsigned long long kk = buf[ss * TPB + tid];
          float d2v = __uint_as_float((unsigned)(kk >> 32));
          int j = (int)(kk & 0xffffffffULL);
          float d2c = fmaxf(d2v, 0.0f);
          float dist = __fsqrt_rn(d2c + SEPS);
          float md = (dist <= MAX_R) ? dist : BIGF;
          if (md < v[15]) {
            bool cg[16];
#pragma unroll
            for (int t = 0; t < 16; t++) cg[t] = (v[t] > md);
#pragma unroll
            for (int t = 15; t >= 1; t--) {
              v[t]  = cg[t - 1] ? v[t - 1]  : (cg[t] ? md : v[t]);
              id[t] = cg[t - 1] ? id[t - 1] : (cg[t] ? j  : id[t]);
            }
            if (cg[0]) { v[0] = md; id[0] = j; }
          }
        }
      }
      cnt = 0;
      float v15 = v[15];
      v15q = fminf(0.0905f, fmaf(v15, v15, 1e-6f));
    }
  }

  for (int ss = 0; ss < 8; ss++) {
    if (ss < cnt) {
      unsigned long long kk = buf[ss * TPB + tid];
      float d2v = __uint_as_float((unsigned)(kk >> 32));
      int j = (int)(kk & 0xffffffffULL);
      float d2c = fmaxf(d2v, 0.0f);
      float dist = __fsqrt_rn(d2c + SEPS);
      float md = (dist <= MAX_R) ? dist : BIGF;
      if (md < v[15]) {
        bool cg[16];
#pragma unroll
        for (int t = 0; t < 16; t++) cg[t] = (v[t] > md);
#pragma unroll
        for (int t = 15; t >= 1; t--) {
          v[t]  = cg[t - 1] ? v[t - 1]  : (cg[t] ? md : v[t]);
          id[t] = cg[t - 1] ? id[t - 1] : (cg[t] ? j  : id[t]);
        }
        if (cg[0]) { v[0] = md; id[0] = j; }
      }
    }
  }

#pragma unroll
  for (int t = 0; t < 16; t++) {
    int o = (s * 16 + t) * BM + cm;
    pvals[o] = v[t];
    pidx[o]  = id[t];
  }
}

// ---------------------------------------------------------------------------
// Kernel B: merge nchunks sorted partial lists (64 thr/block)
// ---------------------------------------------------------------------------
__global__ __launch_bounds__(64) void knn_merge_kernel(
    const float* __restrict__ pvals, const int* __restrict__ pidx,
    int* __restrict__ kidx, float* __restrict__ dout, int nchunks)
{
  const int cm = blockIdx.x * 64 + threadIdx.x;

  unsigned long long key[16];
#pragma unroll
  for (int t = 0; t < 16; t++) {
    int o = t * BM + cm;
    unsigned int vb = __float_as_uint(pvals[o]);
    key[t] = ((unsigned long long)vb << 32) | (unsigned int)pidx[o];
  }
  for (int s = 1; s < nchunks; s++) {
    for (int t2 = 0; t2 < 16; t2++) {
      int o = (s * 16 + t2) * BM + cm;
      unsigned int vb = __float_as_uint(pvals[o]);
      unsigned long long Kk = ((unsigned long long)vb << 32) | (unsigned int)pidx[o];
      if (Kk >= key[15]) break;
      bool cg[16];
#pragma unroll
      for (int t = 0; t < 16; t++) cg[t] = (key[t] > Kk);
#pragma unroll
      for (int t = 15; t >= 1; t--)
        key[t] = cg[t - 1] ? key[t - 1] : (cg[t] ? Kk : key[t]);
      if (cg[0]) key[0] = Kk;
    }
  }
#pragma unroll
  for (int t = 0; t < 16; t++) {
    int j = (int)(key[t] & 0xffffffffULL);
    kidx[cm * K_ + t] = j;
    dout[(size_t)BM * OUT_ + (size_t)cm * K_ + t] = (float)j;
  }
}

// ---------------------------------------------------------------------------
// Pre-kernel: W1/W2/Wm -> bf16 col-major
// ---------------------------------------------------------------------------
__global__ __launch_bounds__(TPB) void convert_weights_kernel(
    const float* __restrict__ W1, const float* __restrict__ W2,
    const float* __restrict__ Wm,
    unsigned short* __restrict__ Wt1, unsigned short* __restrict__ Wt2,
    unsigned short* __restrict__ Wtm)
{
  int t = blockIdx.x * TPB + threadIdx.x;
  if (t < 128 * 256) {
    int col = t >> 8, k = t & 255;
    Wt1[t] = bfu(W1[k * 128 + col]);
  } else if (t < 128 * 256 + 128 * 128) {
    int u = t - 128 * 256;
    int col = u >> 7, k = u & 127;
    Wt2[u] = bfu(W2[k * 128 + col]);
  } else {
    int w = t - (128 * 256 + 128 * 128);
    int col = w >> 7, k = w & 127;
    Wtm[w] = bfu(Wm[k * 256 + col]);
  }
}

// ---------------------------------------------------------------------------
// Kernel C: 2 centers/block, LDS-aliased cn <-> (hb|wbb)  [r36, unchanged]
// ---------------------------------------------------------------------------
__global__ __launch_bounds__(TPB, 5) void fuse_mlp_kernel(
    const float* __restrict__ feats, const int* __restrict__ cidx,
    const int* __restrict__ kidx,
    const float* __restrict__ ln1w, const float* __restrict__ ln1b,
    const unsigned short* __restrict__ Wt1, const float* __restrict__ b1,
    const unsigned short* __restrict__ Wt2, const float* __restrict__ b2,
    const unsigned short* __restrict__ Wtm, const float* __restrict__ bm,
    const float* __restrict__ ln2w, const float* __restrict__ ln2b,
    const float* __restrict__ res_scale,
    float* __restrict__ dout)
{
  const int cm0 = blockIdx.x * 2;
  const int b   = cm0 >> 12;
  const int tid = threadIdx.x;
  const int lane = tid & 63, wv = tid >> 6;

  __shared__ float cf[2][C_];
  __shared__ __align__(16) unsigned short nb[2][K_][136];
  __shared__ __align__(16) char pool[2 * K_ * 272 * 2];
  __shared__ __align__(16) unsigned short fvb[2][136];
  __shared__ float outb[2][OUT_];
  __shared__ float red[4];
  __shared__ int nidx[2][K_];

  typedef unsigned short cn_t[K_][272];
  typedef unsigned short hw_t[K_][136];
  cn_t* cn  = (cn_t*)pool;
  hw_t* hb  = (hw_t*)pool;
  hw_t* wbb = (hw_t*)(pool + 2 * K_ * 136 * 2);

  if (tid < 32) {
    int c = tid >> 4, t = tid & 15;
    nidx[c][t] = kidx[(cm0 + c) * K_ + t];
  }
  __syncthreads();

  {
    for (int t = tid; t < 1088; t += TPB) {
      int c = (t >= 544) ? 1 : 0;
      int u = t - c * 544;
      int row = u >> 5, c4 = u & 31;
      int src = (row == 0) ? cidx[cm0 + c] : nidx[c][row - 1];
      float4 val = *(const float4*)&feats[((size_t)b * N_ + src) * C_ + c4 * 4];
      if (row == 0) {
        *(float4*)&cf[c][c4 * 4] = val;
      } else {
        int r = row - 1, cc = c4 * 4;
        nb[c][r][cc]     = bfu(val.x);
        nb[c][r][cc + 1] = bfu(val.y);
        nb[c][r][cc + 2] = bfu(val.z);
        nb[c][r][cc + 3] = bfu(val.w);
      }
    }
  }
  __syncthreads();

  for (int kk = 0; kk < 4; kk++) {
    int k = wv * 4 + kk;
#pragma unroll
    for (int c = 0; c < 2; c++) {
      float x0 = cf[c][lane];
      float x1 = cf[c][lane + 64];
      float x2 = b2f(nb[c][k][lane]);
      float x3 = b2f(nb[c][k][lane + 64]);
      float ssum = ((x0 + x1) + (x2 + x3));
#pragma unroll
      for (int off = 1; off < 64; off <<= 1) ssum += __shfl_xor(ssum, off, 64);
      float mu = ssum * (1.0f / 256.0f);
      float d0 = x0 - mu, d1 = x1 - mu, d2 = x2 - mu, d3 = x3 - mu;
      float vs = fmaf(d0, d0, fmaf(d1, d1, fmaf(d2, d2, d3 * d3)));
#pragma unroll
      for (int off = 1; off < 64; off <<= 1) vs += __shfl_xor(vs, off, 64);
      float var = vs * (1.0f / 256.0f);
      float rs = 1.0f / __fsqrt_rn(var + LN_EPS_F);
      cn[c][k][lane]       = bfu(fmaf(d0 * rs, ln1w[lane],       ln1b[lane]));
      cn[c][k][lane + 64]  = bfu(fmaf(d1 * rs, ln1w[lane + 64],  ln1b[lane + 64]));
      cn[c][k][lane + 128] = bfu(fmaf(d2 * rs, ln1w[lane + 128], ln1b[lane + 128]));
      cn[c][k][lane + 192] = bfu(fmaf(d3 * rs, ln1w[lane + 192], ln1b[lane + 192]));
    }
  }
  __syncthreads();

  const int r16 = lane & 15;
  const int kg  = lane >> 4;
  const int c0 = (2 * wv) * 16 + r16;
  const int c1 = (2 * wv + 1) * 16 + r16;

  f32x4 a0[2] = {{0.f,0.f,0.f,0.f},{0.f,0.f,0.f,0.f}};
  f32x4 a1[2] = {{0.f,0.f,0.f,0.f},{0.f,0.f,0.f,0.f}};
#pragma unroll
  for (int kt = 0; kt < 8; kt++) {
    int k0 = kt * 32 + kg * 8;
    bf16x8 g0 = *(const bf16x8*)&Wt1[(size_t)c0 * 256 + k0];
    bf16x8 g1 = *(const bf16x8*)&Wt1[(size_t)c1 * 256 + k0];
#pragma unroll
    for (int c = 0; c < 2; c++) {
      bf16x8 af = *(const bf16x8*)&cn[c][r16][k0];
      a0[c] = __builtin_amdgcn_mfma_f32_16x16x32_bf16(af, g0, a0[c], 0, 0, 0);
      a1[c] = __builtin_amdgcn_mfma_f32_16x16x32_bf16(af, g1, a1[c], 0, 0, 0);
    }
  }
  __syncthreads();   // cn reads complete before hb overwrites the pool
#pragma unroll
  for (int c = 0; c < 2; c++)
#pragma unroll
    for (int r = 0; r < 4; r++) {
      int ro = kg * 4 + r;
      hb[c][ro][c0] = bfu(fmaxf(a0[c][r] + b1[c0], 0.f));
      hb[c][ro][c1] = bfu(fmaxf(a1[c][r] + b1[c1], 0.f));
    }
  __syncthreads();

  f32x4 s0[2] = {{0.f,0.f,0.f,0.f},{0.f,0.f,0.f,0.f}};
  f32x4 s1[2] = {{0.f,0.f,0.f,0.f},{0.f,0.f,0.f,0.f}};
#pragma unroll
  for (int kt = 0; kt < 4; kt++) {
    int k0 = kt * 32 + kg * 8;
    bf16x8 g0 = *(const bf16x8*)&Wt2[(size_t)c0 * 128 + k0];
    bf16x8 g1 = *(const bf16x8*)&Wt2[(size_t)c1 * 128 + k0];
#pragma unroll
    for (int c = 0; c < 2; c++) {
      bf16x8 af = *(const bf16x8*)&hb[c][r16][k0];
      s0[c] = __builtin_amdgcn_mfma_f32_16x16x32_bf16(af, g0, s0[c], 0, 0, 0);
      s1[c] = __builtin_amdgcn_mfma_f32_16x16x32_bf16(af, g1, s1[c], 0, 0, 0);
    }
  }
#pragma unroll
  for (int c = 0; c < 2; c++)
#pragma unroll
    for (int r = 0; r < 4; r++) {
      int ro = kg * 4 + r;
      wbb[c][ro][c0] = bfu(1.0f / (1.0f + expf(-(s0[c][r] + b2[c0]))));
      wbb[c][ro][c1] = bfu(1.0f / (1.0f + expf(-(s1[c][r] + b2[c1]))));
    }
  __syncthreads();

  {
    int c = tid >> 7, col = tid & 127;
    float ssum = 0.f;
#pragma unroll
    for (int kq = 0; kq < 16; kq++)
      ssum = fmaf(b2f(nb[c][kq][col]), b2f(wbb[c][kq][col]), ssum);
    float wmean = ssum * (1.0f / 16.0f);
    fvb[c][col] = bfu(fmaf(res_scale[0], wmean, cf[c][col]));
  }
  __syncthreads();

#pragma unroll
  for (int i = 0; i < 4; i++) {
    int cb = (wv * 4 + i) * 16;
    f32x4 acc[2] = {{0.f,0.f,0.f,0.f},{0.f,0.f,0.f,0.f}};
#pragma unroll
    for (int kt = 0; kt < 4; kt++) {
      int k0 = kt * 32 + kg * 8;
      bf16x8 gf = *(const bf16x8*)&Wtm[(size_t)(cb + r16) * 128 + k0];
#pragma unroll
      for (int c = 0; c < 2; c++) {
        bf16x8 af = *(const bf16x8*)&fvb[c][k0];
        acc[c] = __builtin_amdgcn_mfma_f32_16x16x32_bf16(af, gf, acc[c], 0, 0, 0);
      }
    }
    if (kg == 0) {
      int cc = cb + r16;
#pragma unroll
      for (int c = 0; c < 2; c++)
        outb[c][cc] = fmaxf(acc[c][0] + bm[cc], 0.f);
    }
  }
  __syncthreads();

  for (int c = 0; c < 2; c++) {
    float outx = outb[c][tid];
    float s = outx;
#pragma unroll
    for (int off = 1; off < 64; off <<= 1) s += __shfl_xor(s, off, 64);
    if (lane == 0) red[wv] = s;
    __syncthreads();
    float mu = (red[0] + red[1] + red[2] + red[3]) * (1.0f / 256.0f);
    float d = outx - mu;
    float s2 = d * d;
#pragma unroll
    for (int off = 1; off < 64; off <<= 1) s2 += __shfl_xor(s2, off, 64);
    __syncthreads();
    if (lane == 0) red[wv] = s2;
    __syncthreads();
    float var = (red[0] + red[1] + red[2] + red[3]) * (1.0f / 256.0f);
    float rs2 = 1.0f / __fsqrt_rn(var + LN_EPS_F);
    dout[(size_t)(cm0 + c) * OUT_ + tid] = fmaf(d * rs2, ln2w[tid], ln2b[tid]);
    __syncthreads();
  }
}

// ---------------------------------------------------------------------------
extern "C" void kernel_launch(void* const* d_in, const int* in_sizes, int n_in,
                              void* d_out, int out_size, void* d_ws, size_t ws_size,
                              hipStream_t stream) {
  const float* points = (const float*)d_in[0];
  const float* feats  = (const float*)d_in[1];
  const int*   cidx   = (const int*)  d_in[2];
  const float* ln1w   = (const float*)d_in[3];
  const float* ln1b   = (const float*)d_in[4];
  const float* W1     = (const float*)d_in[5];
  const float* b1     = (const float*)d_in[6];
  const float* W2     = (const float*)d_in[7];
  const float* b2     = (const float*)d_in[8];
  const float* Wm     = (const float*)d_in[9];
  const float* bm     = (const float*)d_in[10];
  const float* ln2w   = (const float*)d_in[11];
  const float* ln2b   = (const float*)d_in[12];
  const float* rscale = (const float*)d_in[13];

  float* out = (float*)d_out;
  char*  ws  = (char*)d_ws;

  // choose chunk count by available workspace (deterministic per harness)
  const size_t wsum = (size_t)128 * 256 * 2 + 128 * 128 * 2 + 256 * 128 * 2;
  size_t need32 = 2 * ((size_t)32 * 16 * BM * 4) + (size_t)BM * K_ * 4 + wsum;
  int nchunks = (ws_size >= need32) ? 32 : 16;
  int chunkn  = N_ / nchunks;

  size_t pv_bytes = (size_t)nchunks * 16 * BM * 4;
  float* pvals = (float*)ws;
  int*   pidx  = (int*)(ws + pv_bytes);
  int*   kidx  = (int*)(ws + 2 * pv_bytes);
  unsigned short* Wt1 = (unsigned short*)(ws + 2 * pv_bytes + (size_t)BM * K_ * 4);
  unsigned short* Wt2 = Wt1 + 128 * 256;
  unsigned short* Wtm = Wt2 + 128 * 128;

  size_t smemA = (size_t)chunkn * 16 + 8 * TPB * 8;

  convert_weights_kernel<<<(128 * 256 + 128 * 128 + 256 * 128 + TPB - 1) / TPB,
                           TPB, 0, stream>>>(W1, W2, Wm, Wt1, Wt2, Wtm);
  knn_partial_kernel<<<dim3(nchunks, M_ / TPB, B_), TPB, smemA, stream>>>(
      points, cidx, pvals, pidx, chunkn);
  knn_merge_kernel<<<BM / 64, 64, 0, stream>>>(pvals, pidx, kidx, out, nchunks);
  fuse_mlp_kernel<<<BM / 2, TPB, 0, stream>>>(feats, cidx, kidx,
                                              ln1w, ln1b, Wt1, b1, Wt2, b2, Wtm, bm,
                                              ln2w, ln2b, rscale, out);
}

// Round 38
// 443.138 us; speedup vs baseline: 1.0606x; 1.0606x over previous
//
#include <hip/hip_runtime.h>
#include <hip/hip_bf16.h>
#include <math.h>

#define B_ 4
#define N_ 16384
#define M_ 4096
#define K_ 16
#define C_ 128
#define OUT_ 256
#define S_CHUNKS 16
#define CHUNK 1024
#define TPB 256
#define MAX_R 0.3f
#define BIGF 1e9f
#define LN_EPS_F 1e-5f
#define SEPS 1e-6f
#define BM (B_ * M_)

// KNN exactness (r25, FROZEN): d2 = fma(-2,dot,aq+bq), sq=(x²+z²)+y²,
// dot=fma(c2p2,fma(c1p1,c0p0)), dist=sqrt(d2+eps)<=0.3, (dist,idx) stable.
// r38 = r36 revert (best known 443us). r37's 32-chunk regressed: warm-up
// doubling + merge doubling cancelled the occupancy gain.

typedef __attribute__((ext_vector_type(8))) short bf16x8;
typedef __attribute__((ext_vector_type(4))) float f32x4;

__device__ __forceinline__ unsigned short bfu(float f) {
  __hip_bfloat16 h = __float2bfloat16(f);
  return *reinterpret_cast<unsigned short*>(&h);
}
__device__ __forceinline__ float b2f(unsigned short u) {
  unsigned x = ((unsigned)u) << 16;
  return __uint_as_float(x);
}

// ---------------------------------------------------------------------------
// Kernel A: per-(center, chunk) partial top-16, d2-deferred buffer
// ---------------------------------------------------------------------------
__global__ __launch_bounds__(TPB) void knn_partial_kernel(
    const float* __restrict__ points, const int* __restrict__ cidx,
    float* __restrict__ pvals, int* __restrict__ pidx)
{
#pragma clang fp contract(off)
  const int s  = blockIdx.x;
  const int mg = blockIdx.y;
  const int b  = blockIdx.z;
  const int tid = threadIdx.x;

  __shared__ float4 pts[CHUNK];
  __shared__ unsigned long long buf[8][TPB];

  const int j0 = s * CHUNK;
  for (int e = tid; e < CHUNK; e += TPB) {
    int j = j0 + e;
    float x = points[(b * N_ + j) * 3 + 0];
    float y = points[(b * N_ + j) * 3 + 1];
    float z = points[(b * N_ + j) * 3 + 2];
    float bq = (x * x + z * z) + y * y;      // einsum SSE2 tree
    pts[e] = make_float4(x, y, z, bq);
  }

  const int m  = mg * TPB + tid;
  const int cm = b * M_ + m;
  const int ci = cidx[cm];
  const float cx = points[(b * N_ + ci) * 3 + 0];
  const float cy = points[(b * N_ + ci) * 3 + 1];
  const float cz = points[(b * N_ + ci) * 3 + 2];
  const float aq = (cx * cx + cz * cz) + cy * cy;   // einsum SSE2 tree
  __syncthreads();

  float v[16];
  int   id[16];
#pragma unroll
  for (int t = 0; t < 16; t++) { v[t] = 3.4e38f; id[t] = 0; }
  float v15q = 0.0905f;
  int cnt = 0;

  for (int e = 0; e < CHUNK; e++) {
    float4 p = pts[e];
    float dot = fmaf(cz, p.z, fmaf(cy, p.y, cx * p.x));  // BLAS fma chain
    float d2 = fmaf(-2.0f, dot, aq + p.w);
    if (d2 < v15q) {
      buf[cnt][tid] =
          ((unsigned long long)__float_as_uint(d2) << 32) | (unsigned)(j0 + e);
      cnt++;
    }
    if (__any(cnt == 8)) {
      for (int ss = 0; ss < 8; ss++) {
        if (ss < cnt) {
          unsigned long long kk = buf[ss][tid];
          float d2v = __uint_as_float((unsigned)(kk >> 32));
          int j = (int)(kk & 0xffffffffULL);
          float d2c = fmaxf(d2v, 0.0f);
          float dist = __fsqrt_rn(d2c + SEPS);
          float md = (dist <= MAX_R) ? dist : BIGF;
          if (md < v[15]) {
            bool cg[16];
#pragma unroll
            for (int t = 0; t < 16; t++) cg[t] = (v[t] > md);
#pragma unroll
            for (int t = 15; t >= 1; t--) {
              v[t]  = cg[t - 1] ? v[t - 1]  : (cg[t] ? md : v[t]);
              id[t] = cg[t - 1] ? id[t - 1] : (cg[t] ? j  : id[t]);
            }
            if (cg[0]) { v[0] = md; id[0] = j; }
          }
        }
      }
      cnt = 0;
      float v15 = v[15];
      v15q = fminf(0.0905f, fmaf(v15, v15, 1e-6f));
    }
  }

  for (int ss = 0; ss < 8; ss++) {
    if (ss < cnt) {
      unsigned long long kk = buf[ss][tid];
      float d2v = __uint_as_float((unsigned)(kk >> 32));
      int j = (int)(kk & 0xffffffffULL);
      float d2c = fmaxf(d2v, 0.0f);
      float dist = __fsqrt_rn(d2c + SEPS);
      float md = (dist <= MAX_R) ? dist : BIGF;
      if (md < v[15]) {
        bool cg[16];
#pragma unroll
        for (int t = 0; t < 16; t++) cg[t] = (v[t] > md);
#pragma unroll
        for (int t = 15; t >= 1; t--) {
          v[t]  = cg[t - 1] ? v[t - 1]  : (cg[t] ? md : v[t]);
          id[t] = cg[t - 1] ? id[t - 1] : (cg[t] ? j  : id[t]);
        }
        if (cg[0]) { v[0] = md; id[0] = j; }
      }
    }
  }

#pragma unroll
  for (int t = 0; t < 16; t++) {
    int o = (s * 16 + t) * BM + cm;
    pvals[o] = v[t];
    pidx[o]  = id[t];
  }
}

// ---------------------------------------------------------------------------
// Kernel B: merge S_CHUNKS sorted partial lists (64 thr/block)
// ---------------------------------------------------------------------------
__global__ __launch_bounds__(64) void knn_merge_kernel(
    const float* __restrict__ pvals, const int* __restrict__ pidx,
    int* __restrict__ kidx, float* __restrict__ dout)
{
  const int cm = blockIdx.x * 64 + threadIdx.x;

  unsigned long long key[16];
#pragma unroll
  for (int t = 0; t < 16; t++) {
    int o = t * BM + cm;
    unsigned int vb = __float_as_uint(pvals[o]);
    key[t] = ((unsigned long long)vb << 32) | (unsigned int)pidx[o];
  }
  for (int s = 1; s < S_CHUNKS; s++) {
    for (int t2 = 0; t2 < 16; t2++) {
      int o = (s * 16 + t2) * BM + cm;
      unsigned int vb = __float_as_uint(pvals[o]);
      unsigned long long Kk = ((unsigned long long)vb << 32) | (unsigned int)pidx[o];
      if (Kk >= key[15]) break;
      bool cg[16];
#pragma unroll
      for (int t = 0; t < 16; t++) cg[t] = (key[t] > Kk);
#pragma unroll
      for (int t = 15; t >= 1; t--)
        key[t] = cg[t - 1] ? key[t - 1] : (cg[t] ? Kk : key[t]);
      if (cg[0]) key[0] = Kk;
    }
  }
#pragma unroll
  for (int t = 0; t < 16; t++) {
    int j = (int)(key[t] & 0xffffffffULL);
    kidx[cm * K_ + t] = j;
    dout[(size_t)BM * OUT_ + (size_t)cm * K_ + t] = (float)j;
  }
}

// ---------------------------------------------------------------------------
// Pre-kernel: W1/W2/Wm -> bf16 col-major
// ---------------------------------------------------------------------------
__global__ __launch_bounds__(TPB) void convert_weights_kernel(
    const float* __restrict__ W1, const float* __restrict__ W2,
    const float* __restrict__ Wm,
    unsigned short* __restrict__ Wt1, unsigned short* __restrict__ Wt2,
    unsigned short* __restrict__ Wtm)
{
  int t = blockIdx.x * TPB + threadIdx.x;
  if (t < 128 * 256) {
    int col = t >> 8, k = t & 255;
    Wt1[t] = bfu(W1[k * 128 + col]);
  } else if (t < 128 * 256 + 128 * 128) {
    int u = t - 128 * 256;
    int col = u >> 7, k = u & 127;
    Wt2[u] = bfu(W2[k * 128 + col]);
  } else {
    int w = t - (128 * 256 + 128 * 128);
    int col = w >> 7, k = w & 127;
    Wtm[w] = bfu(Wm[k * 256 + col]);
  }
}

// ---------------------------------------------------------------------------
// Kernel C: 2 centers/block, LDS-aliased cn <-> (hb|wbb), 5 blocks/CU
// ---------------------------------------------------------------------------
__global__ __launch_bounds__(TPB, 5) void fuse_mlp_kernel(
    const float* __restrict__ feats, const int* __restrict__ cidx,
    const int* __restrict__ kidx,
    const float* __restrict__ ln1w, const float* __restrict__ ln1b,
    const unsigned short* __restrict__ Wt1, const float* __restrict__ b1,
    const unsigned short* __restrict__ Wt2, const float* __restrict__ b2,
    const unsigned short* __restrict__ Wtm, const float* __restrict__ bm,
    const float* __restrict__ ln2w, const float* __restrict__ ln2b,
    const float* __restrict__ res_scale,
    float* __restrict__ dout)
{
  const int cm0 = blockIdx.x * 2;
  const int b   = cm0 >> 12;
  const int tid = threadIdx.x;
  const int lane = tid & 63, wv = tid >> 6;

  __shared__ float cf[2][C_];
  __shared__ __align__(16) unsigned short nb[2][K_][136];
  __shared__ __align__(16) char pool[2 * K_ * 272 * 2];
  __shared__ __align__(16) unsigned short fvb[2][136];
  __shared__ float outb[2][OUT_];
  __shared__ float red[4];
  __shared__ int nidx[2][K_];

  typedef unsigned short cn_t[K_][272];
  typedef unsigned short hw_t[K_][136];
  cn_t* cn  = (cn_t*)pool;
  hw_t* hb  = (hw_t*)pool;
  hw_t* wbb = (hw_t*)(pool + 2 * K_ * 136 * 2);

  if (tid < 32) {
    int c = tid >> 4, t = tid & 15;
    nidx[c][t] = kidx[(cm0 + c) * K_ + t];
  }
  __syncthreads();

  {
    for (int t = tid; t < 1088; t += TPB) {
      int c = (t >= 544) ? 1 : 0;
      int u = t - c * 544;
      int row = u >> 5, c4 = u & 31;
      int src = (row == 0) ? cidx[cm0 + c] : nidx[c][row - 1];
      float4 val = *(const float4*)&feats[((size_t)b * N_ + src) * C_ + c4 * 4];
      if (row == 0) {
        *(float4*)&cf[c][c4 * 4] = val;
      } else {
        int r = row - 1, cc = c4 * 4;
        nb[c][r][cc]     = bfu(val.x);
        nb[c][r][cc + 1] = bfu(val.y);
        nb[c][r][cc + 2] = bfu(val.z);
        nb[c][r][cc + 3] = bfu(val.w);
      }
    }
  }
  __syncthreads();

  for (int kk = 0; kk < 4; kk++) {
    int k = wv * 4 + kk;
#pragma unroll
    for (int c = 0; c < 2; c++) {
      float x0 = cf[c][lane];
      float x1 = cf[c][lane + 64];
      float x2 = b2f(nb[c][k][lane]);
      float x3 = b2f(nb[c][k][lane + 64]);
      float ssum = ((x0 + x1) + (x2 + x3));
#pragma unroll
      for (int off = 1; off < 64; off <<= 1) ssum += __shfl_xor(ssum, off, 64);
      float mu = ssum * (1.0f / 256.0f);
      float d0 = x0 - mu, d1 = x1 - mu, d2 = x2 - mu, d3 = x3 - mu;
      float vs = fmaf(d0, d0, fmaf(d1, d1, fmaf(d2, d2, d3 * d3)));
#pragma unroll
      for (int off = 1; off < 64; off <<= 1) vs += __shfl_xor(vs, off, 64);
      float var = vs * (1.0f / 256.0f);
      float rs = 1.0f / __fsqrt_rn(var + LN_EPS_F);
      cn[c][k][lane]       = bfu(fmaf(d0 * rs, ln1w[lane],       ln1b[lane]));
      cn[c][k][lane + 64]  = bfu(fmaf(d1 * rs, ln1w[lane + 64],  ln1b[lane + 64]));
      cn[c][k][lane + 128] = bfu(fmaf(d2 * rs, ln1w[lane + 128], ln1b[lane + 128]));
      cn[c][k][lane + 192] = bfu(fmaf(d3 * rs, ln1w[lane + 192], ln1b[lane + 192]));
    }
  }
  __syncthreads();

  const int r16 = lane & 15;
  const int kg  = lane >> 4;
  const int c0 = (2 * wv) * 16 + r16;
  const int c1 = (2 * wv + 1) * 16 + r16;

  f32x4 a0[2] = {{0.f,0.f,0.f,0.f},{0.f,0.f,0.f,0.f}};
  f32x4 a1[2] = {{0.f,0.f,0.f,0.f},{0.f,0.f,0.f,0.f}};
#pragma unroll
  for (int kt = 0; kt < 8; kt++) {
    int k0 = kt * 32 + kg * 8;
    bf16x8 g0 = *(const bf16x8*)&Wt1[(size_t)c0 * 256 + k0];
    bf16x8 g1 = *(const bf16x8*)&Wt1[(size_t)c1 * 256 + k0];
#pragma unroll
    for (int c = 0; c < 2; c++) {
      bf16x8 af = *(const bf16x8*)&cn[c][r16][k0];
      a0[c] = __builtin_amdgcn_mfma_f32_16x16x32_bf16(af, g0, a0[c], 0, 0, 0);
      a1[c] = __builtin_amdgcn_mfma_f32_16x16x32_bf16(af, g1, a1[c], 0, 0, 0);
    }
  }
  __syncthreads();   // cn reads complete before hb overwrites the pool
#pragma unroll
  for (int c = 0; c < 2; c++)
#pragma unroll
    for (int r = 0; r < 4; r++) {
      int ro = kg * 4 + r;
      hb[c][ro][c0] = bfu(fmaxf(a0[c][r] + b1[c0], 0.f));
      hb[c][ro][c1] = bfu(fmaxf(a1[c][r] + b1[c1], 0.f));
    }
  __syncthreads();

  f32x4 s0[2] = {{0.f,0.f,0.f,0.f},{0.f,0.f,0.f,0.f}};
  f32x4 s1[2] = {{0.f,0.f,0.f,0.f},{0.f,0.f,0.f,0.f}};
#pragma unroll
  for (int kt = 0; kt < 4; kt++) {
    int k0 = kt * 32 + kg * 8;
    bf16x8 g0 = *(const bf16x8*)&Wt2[(size_t)c0 * 128 + k0];
    bf16x8 g1 = *(const bf16x8*)&Wt2[(size_t)c1 * 128 + k0];
#pragma unroll
    for (int c = 0; c < 2; c++) {
      bf16x8 af = *(const bf16x8*)&hb[c][r16][k0];
      s0[c] = __builtin_amdgcn_mfma_f32_16x16x32_bf16(af, g0, s0[c], 0, 0, 0);
      s1[c] = __builtin_amdgcn_mfma_f32_16x16x32_bf16(af, g1, s1[c], 0, 0, 0);
    }
  }
#pragma unroll
  for (int c = 0; c < 2; c++)
#pragma unroll
    for (int r = 0; r < 4; r++) {
      int ro = kg * 4 + r;
      wbb[c][ro][c0] = bfu(1.0f / (1.0f + expf(-(s0[c][r] + b2[c0]))));
      wbb[c][ro][c1] = bfu(1.0f / (1.0f + expf(-(s1[c][r] + b2[c1]))));
    }
  __syncthreads();

  {
    int c = tid >> 7, col = tid & 127;
    float ssum = 0.f;
#pragma unroll
    for (int kq = 0; kq < 16; kq++)
      ssum = fmaf(b2f(nb[c][kq][col]), b2f(wbb[c][kq][col]), ssum);
    float wmean = ssum * (1.0f / 16.0f);
    fvb[c][col] = bfu(fmaf(res_scale[0], wmean, cf[c][col]));
  }
  __syncthreads();

#pragma unroll
  for (int i = 0; i < 4; i++) {
    int cb = (wv * 4 + i) * 16;
    f32x4 acc[2] = {{0.f,0.f,0.f,0.f},{0.f,0.f,0.f,0.f}};
#pragma unroll
    for (int kt = 0; kt < 4; kt++) {
      int k0 = kt * 32 + kg * 8;
      bf16x8 gf = *(const bf16x8*)&Wtm[(size_t)(cb + r16) * 128 + k0];
#pragma unroll
      for (int c = 0; c < 2; c++) {
        bf16x8 af = *(const bf16x8*)&fvb[c][k0];
        acc[c] = __builtin_amdgcn_mfma_f32_16x16x32_bf16(af, gf, acc[c], 0, 0, 0);
      }
    }
    if (kg == 0) {
      int cc = cb + r16;
#pragma unroll
      for (int c = 0; c < 2; c++)
        outb[c][cc] = fmaxf(acc[c][0] + bm[cc], 0.f);
    }
  }
  __syncthreads();

  for (int c = 0; c < 2; c++) {
    float outx = outb[c][tid];
    float s = outx;
#pragma unroll
    for (int off = 1; off < 64; off <<= 1) s += __shfl_xor(s, off, 64);
    if (lane == 0) red[wv] = s;
    __syncthreads();
    float mu = (red[0] + red[1] + red[2] + red[3]) * (1.0f / 256.0f);
    float d = outx - mu;
    float s2 = d * d;
#pragma unroll
    for (int off = 1; off < 64; off <<= 1) s2 += __shfl_xor(s2, off, 64);
    __syncthreads();
    if (lane == 0) red[wv] = s2;
    __syncthreads();
    float var = (red[0] + red[1] + red[2] + red[3]) * (1.0f / 256.0f);
    float rs2 = 1.0f / __fsqrt_rn(var + LN_EPS_F);
    dout[(size_t)(cm0 + c) * OUT_ + tid] = fmaf(d * rs2, ln2w[tid], ln2b[tid]);
    __syncthreads();
  }
}

// ---------------------------------------------------------------------------
extern "C" void kernel_launch(void* const* d_in, const int* in_sizes, int n_in,
                              void* d_out, int out_size, void* d_ws, size_t ws_size,
                              hipStream_t stream) {
  const float* points = (const float*)d_in[0];
  const float* feats  = (const float*)d_in[1];
  const int*   cidx   = (const int*)  d_in[2];
  const float* ln1w   = (const float*)d_in[3];
  const float* ln1b   = (const float*)d_in[4];
  const float* W1     = (const float*)d_in[5];
  const float* b1     = (const float*)d_in[6];
  const float* W2     = (const float*)d_in[7];
  const float* b2     = (const float*)d_in[8];
  const float* Wm     = (const float*)d_in[9];
  const float* bm     = (const float*)d_in[10];
  const float* ln2w   = (const float*)d_in[11];
  const float* ln2b   = (const float*)d_in[12];
  const float* rscale = (const float*)d_in[13];

  float* out = (float*)d_out;
  char*  ws  = (char*)d_ws;
  float* pvals = (float*)ws;
  int*   pidx  = (int*)(ws + 16777216);
  int*   kidx  = (int*)(ws + 33554432);
  unsigned short* Wt1 = (unsigned short*)(ws + 34603008);
  unsigned short* Wt2 = (unsigned short*)(ws + 34603008 + 65536);
  unsigned short* Wtm = (unsigned short*)(ws + 34603008 + 65536 + 32768);

  convert_weights_kernel<<<(128 * 256 + 128 * 128 + 256 * 128 + TPB - 1) / TPB,
                           TPB, 0, stream>>>(W1, W2, Wm, Wt1, Wt2, Wtm);
  knn_partial_kernel<<<dim3(S_CHUNKS, M_ / TPB, B_), TPB, 0, stream>>>(points, cidx, pvals, pidx);
  knn_merge_kernel<<<BM / 64, 64, 0, stream>>>(pvals, pidx, kidx, out);
  fuse_mlp_kernel<<<BM / 2, TPB, 0, stream>>>(feats, cidx, kidx,
                                              ln1w, ln1b, Wt1, b1, Wt2, b2, Wtm, bm,
                                              ln2w, ln2b, rscale, out);
}

// Round 39
// 436.746 us; speedup vs baseline: 1.0762x; 1.0146x over previous
//
#include <hip/hip_runtime.h>
#include <hip/hip_bf16.h>
#include <math.h>

#define B_ 4
#define N_ 16384
#define M_ 4096
#define K_ 16
#define C_ 128
#define OUT_ 256
#define S_CHUNKS 16
#define CHUNK 1024
#define TPB 256
#define MAX_R 0.3f
#define BIGF 1e9f
#define LN_EPS_F 1e-5f
#define SEPS 1e-6f
#define BM (B_ * M_)

// KNN exactness (r25, FROZEN): d2 = fma(-2,dot,aq+bq), sq=(x²+z²)+y²,
// dot=fma(c2p2,fma(c1p1,c0p0)), dist=sqrt(d2+eps)<=0.3, (dist,idx) stable.
// r39: C fast transcendentals — __expf / v_rcp / v_rsq for sigmoid+LN scale.
// All feed bf16-quantized buffers (or fp32 out with 1e4x threshold margin);
// rel-err ~1e-6 is invisible. knn path untouched (Output 1 bit-exact).

typedef __attribute__((ext_vector_type(8))) short bf16x8;
typedef __attribute__((ext_vector_type(4))) float f32x4;

__device__ __forceinline__ unsigned short bfu(float f) {
  __hip_bfloat16 h = __float2bfloat16(f);
  return *reinterpret_cast<unsigned short*>(&h);
}
__device__ __forceinline__ float b2f(unsigned short u) {
  unsigned x = ((unsigned)u) << 16;
  return __uint_as_float(x);
}
__device__ __forceinline__ float fast_sigmoid(float x) {
  return __builtin_amdgcn_rcpf(1.0f + __expf(-x));
}

// ---------------------------------------------------------------------------
// Kernel A: per-(center, chunk) partial top-16, d2-deferred buffer  [FROZEN]
// ---------------------------------------------------------------------------
__global__ __launch_bounds__(TPB) void knn_partial_kernel(
    const float* __restrict__ points, const int* __restrict__ cidx,
    float* __restrict__ pvals, int* __restrict__ pidx)
{
#pragma clang fp contract(off)
  const int s  = blockIdx.x;
  const int mg = blockIdx.y;
  const int b  = blockIdx.z;
  const int tid = threadIdx.x;

  __shared__ float4 pts[CHUNK];
  __shared__ unsigned long long buf[8][TPB];

  const int j0 = s * CHUNK;
  for (int e = tid; e < CHUNK; e += TPB) {
    int j = j0 + e;
    float x = points[(b * N_ + j) * 3 + 0];
    float y = points[(b * N_ + j) * 3 + 1];
    float z = points[(b * N_ + j) * 3 + 2];
    float bq = (x * x + z * z) + y * y;      // einsum SSE2 tree
    pts[e] = make_float4(x, y, z, bq);
  }

  const int m  = mg * TPB + tid;
  const int cm = b * M_ + m;
  const int ci = cidx[cm];
  const float cx = points[(b * N_ + ci) * 3 + 0];
  const float cy = points[(b * N_ + ci) * 3 + 1];
  const float cz = points[(b * N_ + ci) * 3 + 2];
  const float aq = (cx * cx + cz * cz) + cy * cy;   // einsum SSE2 tree
  __syncthreads();

  float v[16];
  int   id[16];
#pragma unroll
  for (int t = 0; t < 16; t++) { v[t] = 3.4e38f; id[t] = 0; }
  float v15q = 0.0905f;
  int cnt = 0;

  for (int e = 0; e < CHUNK; e++) {
    float4 p = pts[e];
    float dot = fmaf(cz, p.z, fmaf(cy, p.y, cx * p.x));  // BLAS fma chain
    float d2 = fmaf(-2.0f, dot, aq + p.w);
    if (d2 < v15q) {
      buf[cnt][tid] =
          ((unsigned long long)__float_as_uint(d2) << 32) | (unsigned)(j0 + e);
      cnt++;
    }
    if (__any(cnt == 8)) {
      for (int ss = 0; ss < 8; ss++) {
        if (ss < cnt) {
          unsigned long long kk = buf[ss][tid];
          float d2v = __uint_as_float((unsigned)(kk >> 32));
          int j = (int)(kk & 0xffffffffULL);
          float d2c = fmaxf(d2v, 0.0f);
          float dist = __fsqrt_rn(d2c + SEPS);
          float md = (dist <= MAX_R) ? dist : BIGF;
          if (md < v[15]) {
            bool cg[16];
#pragma unroll
            for (int t = 0; t < 16; t++) cg[t] = (v[t] > md);
#pragma unroll
            for (int t = 15; t >= 1; t--) {
              v[t]  = cg[t - 1] ? v[t - 1]  : (cg[t] ? md : v[t]);
              id[t] = cg[t - 1] ? id[t - 1] : (cg[t] ? j  : id[t]);
            }
            if (cg[0]) { v[0] = md; id[0] = j; }
          }
        }
      }
      cnt = 0;
      float v15 = v[15];
      v15q = fminf(0.0905f, fmaf(v15, v15, 1e-6f));
    }
  }

  for (int ss = 0; ss < 8; ss++) {
    if (ss < cnt) {
      unsigned long long kk = buf[ss][tid];
      float d2v = __uint_as_float((unsigned)(kk >> 32));
      int j = (int)(kk & 0xffffffffULL);
      float d2c = fmaxf(d2v, 0.0f);
      float dist = __fsqrt_rn(d2c + SEPS);
      float md = (dist <= MAX_R) ? dist : BIGF;
      if (md < v[15]) {
        bool cg[16];
#pragma unroll
        for (int t = 0; t < 16; t++) cg[t] = (v[t] > md);
#pragma unroll
        for (int t = 15; t >= 1; t--) {
          v[t]  = cg[t - 1] ? v[t - 1]  : (cg[t] ? md : v[t]);
          id[t] = cg[t - 1] ? id[t - 1] : (cg[t] ? j  : id[t]);
        }
        if (cg[0]) { v[0] = md; id[0] = j; }
      }
    }
  }

#pragma unroll
  for (int t = 0; t < 16; t++) {
    int o = (s * 16 + t) * BM + cm;
    pvals[o] = v[t];
    pidx[o]  = id[t];
  }
}

// ---------------------------------------------------------------------------
// Kernel B: merge S_CHUNKS sorted partial lists (64 thr/block)  [FROZEN]
// ---------------------------------------------------------------------------
__global__ __launch_bounds__(64) void knn_merge_kernel(
    const float* __restrict__ pvals, const int* __restrict__ pidx,
    int* __restrict__ kidx, float* __restrict__ dout)
{
  const int cm = blockIdx.x * 64 + threadIdx.x;

  unsigned long long key[16];
#pragma unroll
  for (int t = 0; t < 16; t++) {
    int o = t * BM + cm;
    unsigned int vb = __float_as_uint(pvals[o]);
    key[t] = ((unsigned long long)vb << 32) | (unsigned int)pidx[o];
  }
  for (int s = 1; s < S_CHUNKS; s++) {
    for (int t2 = 0; t2 < 16; t2++) {
      int o = (s * 16 + t2) * BM + cm;
      unsigned int vb = __float_as_uint(pvals[o]);
      unsigned long long Kk = ((unsigned long long)vb << 32) | (unsigned int)pidx[o];
      if (Kk >= key[15]) break;
      bool cg[16];
#pragma unroll
      for (int t = 0; t < 16; t++) cg[t] = (key[t] > Kk);
#pragma unroll
      for (int t = 15; t >= 1; t--)
        key[t] = cg[t - 1] ? key[t - 1] : (cg[t] ? Kk : key[t]);
      if (cg[0]) key[0] = Kk;
    }
  }
#pragma unroll
  for (int t = 0; t < 16; t++) {
    int j = (int)(key[t] & 0xffffffffULL);
    kidx[cm * K_ + t] = j;
    dout[(size_t)BM * OUT_ + (size_t)cm * K_ + t] = (float)j;
  }
}

// ---------------------------------------------------------------------------
// Pre-kernel: W1/W2/Wm -> bf16 col-major
// ---------------------------------------------------------------------------
__global__ __launch_bounds__(TPB) void convert_weights_kernel(
    const float* __restrict__ W1, const float* __restrict__ W2,
    const float* __restrict__ Wm,
    unsigned short* __restrict__ Wt1, unsigned short* __restrict__ Wt2,
    unsigned short* __restrict__ Wtm)
{
  int t = blockIdx.x * TPB + threadIdx.x;
  if (t < 128 * 256) {
    int col = t >> 8, k = t & 255;
    Wt1[t] = bfu(W1[k * 128 + col]);
  } else if (t < 128 * 256 + 128 * 128) {
    int u = t - 128 * 256;
    int col = u >> 7, k = u & 127;
    Wt2[u] = bfu(W2[k * 128 + col]);
  } else {
    int w = t - (128 * 256 + 128 * 128);
    int col = w >> 7, k = w & 127;
    Wtm[w] = bfu(Wm[k * 256 + col]);
  }
}

// ---------------------------------------------------------------------------
// Kernel C: 2 centers/block, LDS-aliased, fast transcendentals
// ---------------------------------------------------------------------------
__global__ __launch_bounds__(TPB, 5) void fuse_mlp_kernel(
    const float* __restrict__ feats, const int* __restrict__ cidx,
    const int* __restrict__ kidx,
    const float* __restrict__ ln1w, const float* __restrict__ ln1b,
    const unsigned short* __restrict__ Wt1, const float* __restrict__ b1,
    const unsigned short* __restrict__ Wt2, const float* __restrict__ b2,
    const unsigned short* __restrict__ Wtm, const float* __restrict__ bm,
    const float* __restrict__ ln2w, const float* __restrict__ ln2b,
    const float* __restrict__ res_scale,
    float* __restrict__ dout)
{
  const int cm0 = blockIdx.x * 2;
  const int b   = cm0 >> 12;
  const int tid = threadIdx.x;
  const int lane = tid & 63, wv = tid >> 6;

  __shared__ float cf[2][C_];
  __shared__ __align__(16) unsigned short nb[2][K_][136];
  __shared__ __align__(16) char pool[2 * K_ * 272 * 2];
  __shared__ __align__(16) unsigned short fvb[2][136];
  __shared__ float outb[2][OUT_];
  __shared__ float red[4];
  __shared__ int nidx[2][K_];

  typedef unsigned short cn_t[K_][272];
  typedef unsigned short hw_t[K_][136];
  cn_t* cn  = (cn_t*)pool;
  hw_t* hb  = (hw_t*)pool;
  hw_t* wbb = (hw_t*)(pool + 2 * K_ * 136 * 2);

  if (tid < 32) {
    int c = tid >> 4, t = tid & 15;
    nidx[c][t] = kidx[(cm0 + c) * K_ + t];
  }
  __syncthreads();

  {
    for (int t = tid; t < 1088; t += TPB) {
      int c = (t >= 544) ? 1 : 0;
      int u = t - c * 544;
      int row = u >> 5, c4 = u & 31;
      int src = (row == 0) ? cidx[cm0 + c] : nidx[c][row - 1];
      float4 val = *(const float4*)&feats[((size_t)b * N_ + src) * C_ + c4 * 4];
      if (row == 0) {
        *(float4*)&cf[c][c4 * 4] = val;
      } else {
        int r = row - 1, cc = c4 * 4;
        nb[c][r][cc]     = bfu(val.x);
        nb[c][r][cc + 1] = bfu(val.y);
        nb[c][r][cc + 2] = bfu(val.z);
        nb[c][r][cc + 3] = bfu(val.w);
      }
    }
  }
  __syncthreads();

  for (int kk = 0; kk < 4; kk++) {
    int k = wv * 4 + kk;
#pragma unroll
    for (int c = 0; c < 2; c++) {
      float x0 = cf[c][lane];
      float x1 = cf[c][lane + 64];
      float x2 = b2f(nb[c][k][lane]);
      float x3 = b2f(nb[c][k][lane + 64]);
      float ssum = ((x0 + x1) + (x2 + x3));
#pragma unroll
      for (int off = 1; off < 64; off <<= 1) ssum += __shfl_xor(ssum, off, 64);
      float mu = ssum * (1.0f / 256.0f);
      float d0 = x0 - mu, d1 = x1 - mu, d2 = x2 - mu, d3 = x3 - mu;
      float vs = fmaf(d0, d0, fmaf(d1, d1, fmaf(d2, d2, d3 * d3)));
#pragma unroll
      for (int off = 1; off < 64; off <<= 1) vs += __shfl_xor(vs, off, 64);
      float var = vs * (1.0f / 256.0f);
      float rs = __builtin_amdgcn_rsqf(var + LN_EPS_F);   // v_rsq (bf16-safe)
      cn[c][k][lane]       = bfu(fmaf(d0 * rs, ln1w[lane],       ln1b[lane]));
      cn[c][k][lane + 64]  = bfu(fmaf(d1 * rs, ln1w[lane + 64],  ln1b[lane + 64]));
      cn[c][k][lane + 128] = bfu(fmaf(d2 * rs, ln1w[lane + 128], ln1b[lane + 128]));
      cn[c][k][lane + 192] = bfu(fmaf(d3 * rs, ln1w[lane + 192], ln1b[lane + 192]));
    }
  }
  __syncthreads();

  const int r16 = lane & 15;
  const int kg  = lane >> 4;
  const int c0 = (2 * wv) * 16 + r16;
  const int c1 = (2 * wv + 1) * 16 + r16;

  f32x4 a0[2] = {{0.f,0.f,0.f,0.f},{0.f,0.f,0.f,0.f}};
  f32x4 a1[2] = {{0.f,0.f,0.f,0.f},{0.f,0.f,0.f,0.f}};
#pragma unroll
  for (int kt = 0; kt < 8; kt++) {
    int k0 = kt * 32 + kg * 8;
    bf16x8 g0 = *(const bf16x8*)&Wt1[(size_t)c0 * 256 + k0];
    bf16x8 g1 = *(const bf16x8*)&Wt1[(size_t)c1 * 256 + k0];
#pragma unroll
    for (int c = 0; c < 2; c++) {
      bf16x8 af = *(const bf16x8*)&cn[c][r16][k0];
      a0[c] = __builtin_amdgcn_mfma_f32_16x16x32_bf16(af, g0, a0[c], 0, 0, 0);
      a1[c] = __builtin_amdgcn_mfma_f32_16x16x32_bf16(af, g1, a1[c], 0, 0, 0);
    }
  }
  __syncthreads();   // cn reads complete before hb overwrites the pool
#pragma unroll
  for (int c = 0; c < 2; c++)
#pragma unroll
    for (int r = 0; r < 4; r++) {
      int ro = kg * 4 + r;
      hb[c][ro][c0] = bfu(fmaxf(a0[c][r] + b1[c0], 0.f));
      hb[c][ro][c1] = bfu(fmaxf(a1[c][r] + b1[c1], 0.f));
    }
  __syncthreads();

  f32x4 s0[2] = {{0.f,0.f,0.f,0.f},{0.f,0.f,0.f,0.f}};
  f32x4 s1[2] = {{0.f,0.f,0.f,0.f},{0.f,0.f,0.f,0.f}};
#pragma unroll
  for (int kt = 0; kt < 4; kt++) {
    int k0 = kt * 32 + kg * 8;
    bf16x8 g0 = *(const bf16x8*)&Wt2[(size_t)c0 * 128 + k0];
    bf16x8 g1 = *(const bf16x8*)&Wt2[(size_t)c1 * 128 + k0];
#pragma unroll
    for (int c = 0; c < 2; c++) {
      bf16x8 af = *(const bf16x8*)&hb[c][r16][k0];
      s0[c] = __builtin_amdgcn_mfma_f32_16x16x32_bf16(af, g0, s0[c], 0, 0, 0);
      s1[c] = __builtin_amdgcn_mfma_f32_16x16x32_bf16(af, g1, s1[c], 0, 0, 0);
    }
  }
#pragma unroll
  for (int c = 0; c < 2; c++)
#pragma unroll
    for (int r = 0; r < 4; r++) {
      int ro = kg * 4 + r;
      wbb[c][ro][c0] = bfu(fast_sigmoid(s0[c][r] + b2[c0]));
      wbb[c][ro][c1] = bfu(fast_sigmoid(s1[c][r] + b2[c1]));
    }
  __syncthreads();

  {
    int c = tid >> 7, col = tid & 127;
    float ssum = 0.f;
#pragma unroll
    for (int kq = 0; kq < 16; kq++)
      ssum = fmaf(b2f(nb[c][kq][col]), b2f(wbb[c][kq][col]), ssum);
    float wmean = ssum * (1.0f / 16.0f);
    fvb[c][col] = bfu(fmaf(res_scale[0], wmean, cf[c][col]));
  }
  __syncthreads();

#pragma unroll
  for (int i = 0; i < 4; i++) {
    int cb = (wv * 4 + i) * 16;
    f32x4 acc[2] = {{0.f,0.f,0.f,0.f},{0.f,0.f,0.f,0.f}};
#pragma unroll
    for (int kt = 0; kt < 4; kt++) {
      int k0 = kt * 32 + kg * 8;
      bf16x8 gf = *(const bf16x8*)&Wtm[(size_t)(cb + r16) * 128 + k0];
#pragma unroll
      for (int c = 0; c < 2; c++) {
        bf16x8 af = *(const bf16x8*)&fvb[c][k0];
        acc[c] = __builtin_amdgcn_mfma_f32_16x16x32_bf16(af, gf, acc[c], 0, 0, 0);
      }
    }
    if (kg == 0) {
      int cc = cb + r16;
#pragma unroll
      for (int c = 0; c < 2; c++)
        outb[c][cc] = fmaxf(acc[c][0] + bm[cc], 0.f);
    }
  }
  __syncthreads();

  for (int c = 0; c < 2; c++) {
    float outx = outb[c][tid];
    float s = outx;
#pragma unroll
    for (int off = 1; off < 64; off <<= 1) s += __shfl_xor(s, off, 64);
    if (lane == 0) red[wv] = s;
    __syncthreads();
    float mu = (red[0] + red[1] + red[2] + red[3]) * (1.0f / 256.0f);
    float d = outx - mu;
    float s2 = d * d;
#pragma unroll
    for (int off = 1; off < 64; off <<= 1) s2 += __shfl_xor(s2, off, 64);
    __syncthreads();
    if (lane == 0) red[wv] = s2;
    __syncthreads();
    float var = (red[0] + red[1] + red[2] + red[3]) * (1.0f / 256.0f);
    float rs2 = __builtin_amdgcn_rsqf(var + LN_EPS_F);   // v_rsq (margin 1e4x)
    dout[(size_t)(cm0 + c) * OUT_ + tid] = fmaf(d * rs2, ln2w[tid], ln2b[tid]);
    __syncthreads();
  }
}

// ---------------------------------------------------------------------------
extern "C" void kernel_launch(void* const* d_in, const int* in_sizes, int n_in,
                              void* d_out, int out_size, void* d_ws, size_t ws_size,
                              hipStream_t stream) {
  const float* points = (const float*)d_in[0];
  const float* feats  = (const float*)d_in[1];
  const int*   cidx   = (const int*)  d_in[2];
  const float* ln1w   = (const float*)d_in[3];
  const float* ln1b   = (const float*)d_in[4];
  const float* W1     = (const float*)d_in[5];
  const float* b1     = (const float*)d_in[6];
  const float* W2     = (const float*)d_in[7];
  const float* b2     = (const float*)d_in[8];
  const float* Wm     = (const float*)d_in[9];
  const float* bm     = (const float*)d_in[10];
  const float* ln2w   = (const float*)d_in[11];
  const float* ln2b   = (const float*)d_in[12];
  const float* rscale = (const float*)d_in[13];

  float* out = (float*)d_out;
  char*  ws  = (char*)d_ws;
  float* pvals = (float*)ws;
  int*   pidx  = (int*)(ws + 16777216);
  int*   kidx  = (int*)(ws + 33554432);
  unsigned short* Wt1 = (unsigned short*)(ws + 34603008);
  unsigned short* Wt2 = (unsigned short*)(ws + 34603008 + 65536);
  unsigned short* Wtm = (unsigned short*)(ws + 34603008 + 65536 + 32768);

  convert_weights_kernel<<<(128 * 256 + 128 * 128 + 256 * 128 + TPB - 1) / TPB,
                           TPB, 0, stream>>>(W1, W2, Wm, Wt1, Wt2, Wtm);
  knn_partial_kernel<<<dim3(S_CHUNKS, M_ / TPB, B_), TPB, 0, stream>>>(points, cidx, pvals, pidx);
  knn_merge_kernel<<<BM / 64, 64, 0, stream>>>(pvals, pidx, kidx, out);
  fuse_mlp_kernel<<<BM / 2, TPB, 0, stream>>>(feats, cidx, kidx,
                                              ln1w, ln1b, Wt1, b1, Wt2, b2, Wtm, bm,
                                              ln2w, ln2b, rscale, out);
}

// Round 40
// 411.015 us; speedup vs baseline: 1.1435x; 1.0626x over previous
//
#include <hip/hip_runtime.h>
#include <hip/hip_bf16.h>
#include <math.h>

#define B_ 4
#define N_ 16384
#define M_ 4096
#define K_ 16
#define C_ 128
#define OUT_ 256
#define S_CHUNKS 16
#define CHUNK 1024
#define TPB 256
#define MAX_R 0.3f
#define BIGF 1e9f
#define LN_EPS_F 1e-5f
#define SEPS 1e-6f
#define BM (B_ * M_)

// KNN exactness (r25, FROZEN): d2 = fma(-2,dot,aq+bq), sq=(x²+z²)+y²,
// dot=fma(c2p2,fma(c1p1,c0p0)), dist=sqrt(d2+eps)<=0.3, (dist,idx) stable.
// r40: A hot loop unrolled x4 with ONE __any(cnt>=8) drain check per group;
// buf deepened to 12 (max 7+4=11). Append order unchanged => bit-identical.

typedef __attribute__((ext_vector_type(8))) short bf16x8;
typedef __attribute__((ext_vector_type(4))) float f32x4;

__device__ __forceinline__ unsigned short bfu(float f) {
  __hip_bfloat16 h = __float2bfloat16(f);
  return *reinterpret_cast<unsigned short*>(&h);
}
__device__ __forceinline__ float b2f(unsigned short u) {
  unsigned x = ((unsigned)u) << 16;
  return __uint_as_float(x);
}
__device__ __forceinline__ float fast_sigmoid(float x) {
  return __builtin_amdgcn_rcpf(1.0f + __expf(-x));
}

// ---------------------------------------------------------------------------
// Kernel A: per-(center, chunk) partial top-16, d2-deferred, 4x-unrolled
// ---------------------------------------------------------------------------
__global__ __launch_bounds__(TPB) void knn_partial_kernel(
    const float* __restrict__ points, const int* __restrict__ cidx,
    float* __restrict__ pvals, int* __restrict__ pidx)
{
#pragma clang fp contract(off)
  const int s  = blockIdx.x;
  const int mg = blockIdx.y;
  const int b  = blockIdx.z;
  const int tid = threadIdx.x;

  __shared__ float4 pts[CHUNK];
  __shared__ unsigned long long buf[12][TPB];

  const int j0 = s * CHUNK;
  for (int e = tid; e < CHUNK; e += TPB) {
    int j = j0 + e;
    float x = points[(b * N_ + j) * 3 + 0];
    float y = points[(b * N_ + j) * 3 + 1];
    float z = points[(b * N_ + j) * 3 + 2];
    float bq = (x * x + z * z) + y * y;      // einsum SSE2 tree
    pts[e] = make_float4(x, y, z, bq);
  }

  const int m  = mg * TPB + tid;
  const int cm = b * M_ + m;
  const int ci = cidx[cm];
  const float cx = points[(b * N_ + ci) * 3 + 0];
  const float cy = points[(b * N_ + ci) * 3 + 1];
  const float cz = points[(b * N_ + ci) * 3 + 2];
  const float aq = (cx * cx + cz * cz) + cy * cy;   // einsum SSE2 tree
  __syncthreads();

  float v[16];
  int   id[16];
#pragma unroll
  for (int t = 0; t < 16; t++) { v[t] = 3.4e38f; id[t] = 0; }
  float v15q = 0.0905f;
  int cnt = 0;

  for (int e0 = 0; e0 < CHUNK; e0 += 4) {
#pragma unroll
    for (int u = 0; u < 4; u++) {
      int e = e0 + u;
      float4 p = pts[e];
      float dot = fmaf(cz, p.z, fmaf(cy, p.y, cx * p.x));  // BLAS fma chain
      float d2 = fmaf(-2.0f, dot, aq + p.w);
      if (d2 < v15q) {
        buf[cnt][tid] =
            ((unsigned long long)__float_as_uint(d2) << 32) | (unsigned)(j0 + e);
        cnt++;
      }
    }
    if (__any(cnt >= 8)) {
      for (int ss = 0; ss < 12; ss++) {
        if (ss < cnt) {
          unsigned long long kk = buf[ss][tid];
          float d2v = __uint_as_float((unsigned)(kk >> 32));
          int j = (int)(kk & 0xffffffffULL);
          float d2c = fmaxf(d2v, 0.0f);
          float dist = __fsqrt_rn(d2c + SEPS);
          float md = (dist <= MAX_R) ? dist : BIGF;
          if (md < v[15]) {
            bool cg[16];
#pragma unroll
            for (int t = 0; t < 16; t++) cg[t] = (v[t] > md);
#pragma unroll
            for (int t = 15; t >= 1; t--) {
              v[t]  = cg[t - 1] ? v[t - 1]  : (cg[t] ? md : v[t]);
              id[t] = cg[t - 1] ? id[t - 1] : (cg[t] ? j  : id[t]);
            }
            if (cg[0]) { v[0] = md; id[0] = j; }
          }
        }
      }
      cnt = 0;
      float v15 = v[15];
      v15q = fminf(0.0905f, fmaf(v15, v15, 1e-6f));
    }
  }

  // final drain (up to 12 buffered entries)
  for (int ss = 0; ss < 12; ss++) {
    if (ss < cnt) {
      unsigned long long kk = buf[ss][tid];
      float d2v = __uint_as_float((unsigned)(kk >> 32));
      int j = (int)(kk & 0xffffffffULL);
      float d2c = fmaxf(d2v, 0.0f);
      float dist = __fsqrt_rn(d2c + SEPS);
      float md = (dist <= MAX_R) ? dist : BIGF;
      if (md < v[15]) {
        bool cg[16];
#pragma unroll
        for (int t = 0; t < 16; t++) cg[t] = (v[t] > md);
#pragma unroll
        for (int t = 15; t >= 1; t--) {
          v[t]  = cg[t - 1] ? v[t - 1]  : (cg[t] ? md : v[t]);
          id[t] = cg[t - 1] ? id[t - 1] : (cg[t] ? j  : id[t]);
        }
        if (cg[0]) { v[0] = md; id[0] = j; }
      }
    }
  }

#pragma unroll
  for (int t = 0; t < 16; t++) {
    int o = (s * 16 + t) * BM + cm;
    pvals[o] = v[t];
    pidx[o]  = id[t];
  }
}

// ---------------------------------------------------------------------------
// Kernel B: merge S_CHUNKS sorted partial lists (64 thr/block)  [FROZEN]
// ---------------------------------------------------------------------------
__global__ __launch_bounds__(64) void knn_merge_kernel(
    const float* __restrict__ pvals, const int* __restrict__ pidx,
    int* __restrict__ kidx, float* __restrict__ dout)
{
  const int cm = blockIdx.x * 64 + threadIdx.x;

  unsigned long long key[16];
#pragma unroll
  for (int t = 0; t < 16; t++) {
    int o = t * BM + cm;
    unsigned int vb = __float_as_uint(pvals[o]);
    key[t] = ((unsigned long long)vb << 32) | (unsigned int)pidx[o];
  }
  for (int s = 1; s < S_CHUNKS; s++) {
    for (int t2 = 0; t2 < 16; t2++) {
      int o = (s * 16 + t2) * BM + cm;
      unsigned int vb = __float_as_uint(pvals[o]);
      unsigned long long Kk = ((unsigned long long)vb << 32) | (unsigned int)pidx[o];
      if (Kk >= key[15]) break;
      bool cg[16];
#pragma unroll
      for (int t = 0; t < 16; t++) cg[t] = (key[t] > Kk);
#pragma unroll
      for (int t = 15; t >= 1; t--)
        key[t] = cg[t - 1] ? key[t - 1] : (cg[t] ? Kk : key[t]);
      if (cg[0]) key[0] = Kk;
    }
  }
#pragma unroll
  for (int t = 0; t < 16; t++) {
    int j = (int)(key[t] & 0xffffffffULL);
    kidx[cm * K_ + t] = j;
    dout[(size_t)BM * OUT_ + (size_t)cm * K_ + t] = (float)j;
  }
}

// ---------------------------------------------------------------------------
// Pre-kernel: W1/W2/Wm -> bf16 col-major
// ---------------------------------------------------------------------------
__global__ __launch_bounds__(TPB) void convert_weights_kernel(
    const float* __restrict__ W1, const float* __restrict__ W2,
    const float* __restrict__ Wm,
    unsigned short* __restrict__ Wt1, unsigned short* __restrict__ Wt2,
    unsigned short* __restrict__ Wtm)
{
  int t = blockIdx.x * TPB + threadIdx.x;
  if (t < 128 * 256) {
    int col = t >> 8, k = t & 255;
    Wt1[t] = bfu(W1[k * 128 + col]);
  } else if (t < 128 * 256 + 128 * 128) {
    int u = t - 128 * 256;
    int col = u >> 7, k = u & 127;
    Wt2[u] = bfu(W2[k * 128 + col]);
  } else {
    int w = t - (128 * 256 + 128 * 128);
    int col = w >> 7, k = w & 127;
    Wtm[w] = bfu(Wm[k * 256 + col]);
  }
}

// ---------------------------------------------------------------------------
// Kernel C: 2 centers/block, LDS-aliased, fast transcendentals  [r39]
// ---------------------------------------------------------------------------
__global__ __launch_bounds__(TPB, 5) void fuse_mlp_kernel(
    const float* __restrict__ feats, const int* __restrict__ cidx,
    const int* __restrict__ kidx,
    const float* __restrict__ ln1w, const float* __restrict__ ln1b,
    const unsigned short* __restrict__ Wt1, const float* __restrict__ b1,
    const unsigned short* __restrict__ Wt2, const float* __restrict__ b2,
    const unsigned short* __restrict__ Wtm, const float* __restrict__ bm,
    const float* __restrict__ ln2w, const float* __restrict__ ln2b,
    const float* __restrict__ res_scale,
    float* __restrict__ dout)
{
  const int cm0 = blockIdx.x * 2;
  const int b   = cm0 >> 12;
  const int tid = threadIdx.x;
  const int lane = tid & 63, wv = tid >> 6;

  __shared__ float cf[2][C_];
  __shared__ __align__(16) unsigned short nb[2][K_][136];
  __shared__ __align__(16) char pool[2 * K_ * 272 * 2];
  __shared__ __align__(16) unsigned short fvb[2][136];
  __shared__ float outb[2][OUT_];
  __shared__ float red[4];
  __shared__ int nidx[2][K_];

  typedef unsigned short cn_t[K_][272];
  typedef unsigned short hw_t[K_][136];
  cn_t* cn  = (cn_t*)pool;
  hw_t* hb  = (hw_t*)pool;
  hw_t* wbb = (hw_t*)(pool + 2 * K_ * 136 * 2);

  if (tid < 32) {
    int c = tid >> 4, t = tid & 15;
    nidx[c][t] = kidx[(cm0 + c) * K_ + t];
  }
  __syncthreads();

  {
    for (int t = tid; t < 1088; t += TPB) {
      int c = (t >= 544) ? 1 : 0;
      int u = t - c * 544;
      int row = u >> 5, c4 = u & 31;
      int src = (row == 0) ? cidx[cm0 + c] : nidx[c][row - 1];
      float4 val = *(const float4*)&feats[((size_t)b * N_ + src) * C_ + c4 * 4];
      if (row == 0) {
        *(float4*)&cf[c][c4 * 4] = val;
      } else {
        int r = row - 1, cc = c4 * 4;
        nb[c][r][cc]     = bfu(val.x);
        nb[c][r][cc + 1] = bfu(val.y);
        nb[c][r][cc + 2] = bfu(val.z);
        nb[c][r][cc + 3] = bfu(val.w);
      }
    }
  }
  __syncthreads();

  for (int kk = 0; kk < 4; kk++) {
    int k = wv * 4 + kk;
#pragma unroll
    for (int c = 0; c < 2; c++) {
      float x0 = cf[c][lane];
      float x1 = cf[c][lane + 64];
      float x2 = b2f(nb[c][k][lane]);
      float x3 = b2f(nb[c][k][lane + 64]);
      float ssum = ((x0 + x1) + (x2 + x3));
#pragma unroll
      for (int off = 1; off < 64; off <<= 1) ssum += __shfl_xor(ssum, off, 64);
      float mu = ssum * (1.0f / 256.0f);
      float d0 = x0 - mu, d1 = x1 - mu, d2 = x2 - mu, d3 = x3 - mu;
      float vs = fmaf(d0, d0, fmaf(d1, d1, fmaf(d2, d2, d3 * d3)));
#pragma unroll
      for (int off = 1; off < 64; off <<= 1) vs += __shfl_xor(vs, off, 64);
      float var = vs * (1.0f / 256.0f);
      float rs = __builtin_amdgcn_rsqf(var + LN_EPS_F);
      cn[c][k][lane]       = bfu(fmaf(d0 * rs, ln1w[lane],       ln1b[lane]));
      cn[c][k][lane + 64]  = bfu(fmaf(d1 * rs, ln1w[lane + 64],  ln1b[lane + 64]));
      cn[c][k][lane + 128] = bfu(fmaf(d2 * rs, ln1w[lane + 128], ln1b[lane + 128]));
      cn[c][k][lane + 192] = bfu(fmaf(d3 * rs, ln1w[lane + 192], ln1b[lane + 192]));
    }
  }
  __syncthreads();

  const int r16 = lane & 15;
  const int kg  = lane >> 4;
  const int c0 = (2 * wv) * 16 + r16;
  const int c1 = (2 * wv + 1) * 16 + r16;

  f32x4 a0[2] = {{0.f,0.f,0.f,0.f},{0.f,0.f,0.f,0.f}};
  f32x4 a1[2] = {{0.f,0.f,0.f,0.f},{0.f,0.f,0.f,0.f}};
#pragma unroll
  for (int kt = 0; kt < 8; kt++) {
    int k0 = kt * 32 + kg * 8;
    bf16x8 g0 = *(const bf16x8*)&Wt1[(size_t)c0 * 256 + k0];
    bf16x8 g1 = *(const bf16x8*)&Wt1[(size_t)c1 * 256 + k0];
#pragma unroll
    for (int c = 0; c < 2; c++) {
      bf16x8 af = *(const bf16x8*)&cn[c][r16][k0];
      a0[c] = __builtin_amdgcn_mfma_f32_16x16x32_bf16(af, g0, a0[c], 0, 0, 0);
      a1[c] = __builtin_amdgcn_mfma_f32_16x16x32_bf16(af, g1, a1[c], 0, 0, 0);
    }
  }
  __syncthreads();   // cn reads complete before hb overwrites the pool
#pragma unroll
  for (int c = 0; c < 2; c++)
#pragma unroll
    for (int r = 0; r < 4; r++) {
      int ro = kg * 4 + r;
      hb[c][ro][c0] = bfu(fmaxf(a0[c][r] + b1[c0], 0.f));
      hb[c][ro][c1] = bfu(fmaxf(a1[c][r] + b1[c1], 0.f));
    }
  __syncthreads();

  f32x4 s0[2] = {{0.f,0.f,0.f,0.f},{0.f,0.f,0.f,0.f}};
  f32x4 s1[2] = {{0.f,0.f,0.f,0.f},{0.f,0.f,0.f,0.f}};
#pragma unroll
  for (int kt = 0; kt < 4; kt++) {
    int k0 = kt * 32 + kg * 8;
    bf16x8 g0 = *(const bf16x8*)&Wt2[(size_t)c0 * 128 + k0];
    bf16x8 g1 = *(const bf16x8*)&Wt2[(size_t)c1 * 128 + k0];
#pragma unroll
    for (int c = 0; c < 2; c++) {
      bf16x8 af = *(const bf16x8*)&hb[c][r16][k0];
      s0[c] = __builtin_amdgcn_mfma_f32_16x16x32_bf16(af, g0, s0[c], 0, 0, 0);
      s1[c] = __builtin_amdgcn_mfma_f32_16x16x32_bf16(af, g1, s1[c], 0, 0, 0);
    }
  }
#pragma unroll
  for (int c = 0; c < 2; c++)
#pragma unroll
    for (int r = 0; r < 4; r++) {
      int ro = kg * 4 + r;
      wbb[c][ro][c0] = bfu(fast_sigmoid(s0[c][r] + b2[c0]));
      wbb[c][ro][c1] = bfu(fast_sigmoid(s1[c][r] + b2[c1]));
    }
  __syncthreads();

  {
    int c = tid >> 7, col = tid & 127;
    float ssum = 0.f;
#pragma unroll
    for (int kq = 0; kq < 16; kq++)
      ssum = fmaf(b2f(nb[c][kq][col]), b2f(wbb[c][kq][col]), ssum);
    float wmean = ssum * (1.0f / 16.0f);
    fvb[c][col] = bfu(fmaf(res_scale[0], wmean, cf[c][col]));
  }
  __syncthreads();

#pragma unroll
  for (int i = 0; i < 4; i++) {
    int cb = (wv * 4 + i) * 16;
    f32x4 acc[2] = {{0.f,0.f,0.f,0.f},{0.f,0.f,0.f,0.f}};
#pragma unroll
    for (int kt = 0; kt < 4; kt++) {
      int k0 = kt * 32 + kg * 8;
      bf16x8 gf = *(const bf16x8*)&Wtm[(size_t)(cb + r16) * 128 + k0];
#pragma unroll
      for (int c = 0; c < 2; c++) {
        bf16x8 af = *(const bf16x8*)&fvb[c][k0];
        acc[c] = __builtin_amdgcn_mfma_f32_16x16x32_bf16(af, gf, acc[c], 0, 0, 0);
      }
    }
    if (kg == 0) {
      int cc = cb + r16;
#pragma unroll
      for (int c = 0; c < 2; c++)
        outb[c][cc] = fmaxf(acc[c][0] + bm[cc], 0.f);
    }
  }
  __syncthreads();

  for (int c = 0; c < 2; c++) {
    float outx = outb[c][tid];
    float s = outx;
#pragma unroll
    for (int off = 1; off < 64; off <<= 1) s += __shfl_xor(s, off, 64);
    if (lane == 0) red[wv] = s;
    __syncthreads();
    float mu = (red[0] + red[1] + red[2] + red[3]) * (1.0f / 256.0f);
    float d = outx - mu;
    float s2 = d * d;
#pragma unroll
    for (int off = 1; off < 64; off <<= 1) s2 += __shfl_xor(s2, off, 64);
    __syncthreads();
    if (lane == 0) red[wv] = s2;
    __syncthreads();
    float var = (red[0] + red[1] + red[2] + red[3]) * (1.0f / 256.0f);
    float rs2 = __builtin_amdgcn_rsqf(var + LN_EPS_F);
    dout[(size_t)(cm0 + c) * OUT_ + tid] = fmaf(d * rs2, ln2w[tid], ln2b[tid]);
    __syncthreads();
  }
}

// ---------------------------------------------------------------------------
extern "C" void kernel_launch(void* const* d_in, const int* in_sizes, int n_in,
                              void* d_out, int out_size, void* d_ws, size_t ws_size,
                              hipStream_t stream) {
  const float* points = (const float*)d_in[0];
  const float* feats  = (const float*)d_in[1];
  const int*   cidx   = (const int*)  d_in[2];
  const float* ln1w   = (const float*)d_in[3];
  const float* ln1b   = (const float*)d_in[4];
  const float* W1     = (const float*)d_in[5];
  const float* b1     = (const float*)d_in[6];
  const float* W2     = (const float*)d_in[7];
  const float* b2     = (const float*)d_in[8];
  const float* Wm     = (const float*)d_in[9];
  const float* bm     = (const float*)d_in[10];
  const float* ln2w   = (const float*)d_in[11];
  const float* ln2b   = (const float*)d_in[12];
  const float* rscale = (const float*)d_in[13];

  float* out = (float*)d_out;
  char*  ws  = (char*)d_ws;
  float* pvals = (float*)ws;
  int*   pidx  = (int*)(ws + 16777216);
  int*   kidx  = (int*)(ws + 33554432);
  unsigned short* Wt1 = (unsigned short*)(ws + 34603008);
  unsigned short* Wt2 = (unsigned short*)(ws + 34603008 + 65536);
  unsigned short* Wtm = (unsigned short*)(ws + 34603008 + 65536 + 32768);

  convert_weights_kernel<<<(128 * 256 + 128 * 128 + 256 * 128 + TPB - 1) / TPB,
                           TPB, 0, stream>>>(W1, W2, Wm, Wt1, Wt2, Wtm);
  knn_partial_kernel<<<dim3(S_CHUNKS, M_ / TPB, B_), TPB, 0, stream>>>(points, cidx, pvals, pidx);
  knn_merge_kernel<<<BM / 64, 64, 0, stream>>>(pvals, pidx, kidx, out);
  fuse_mlp_kernel<<<BM / 2, TPB, 0, stream>>>(feats, cidx, kidx,
                                              ln1w, ln1b, Wt1, b1, Wt2, b2, Wtm, bm,
                                              ln2w, ln2b, rscale, out);
}

// Round 41
// 372.053 us; speedup vs baseline: 1.2633x; 1.1047x over previous
//
#include <hip/hip_runtime.h>
#include <hip/hip_bf16.h>
#include <math.h>

#define B_ 4
#define N_ 16384
#define M_ 4096
#define K_ 16
#define C_ 128
#define OUT_ 256
#define S_CHUNKS 16
#define CHUNK 1024
#define TPB 256
#define MAX_R 0.3f
#define BIGF 1e9f
#define LN_EPS_F 1e-5f
#define SEPS 1e-6f
#define BM (B_ * M_)

// KNN exactness (r25, FROZEN). r40: A 4x-unrolled deferred buffer (<=200us).
// r41: C -> 4 centers/block, 512 thr: 1 B-frag load feeds 4 MFMAs (2x the
// r33 amortization), weight L2 traffic halves. LDS 58.3KB = 2 blocks/CU x
// 8 waves = 16 waves/CU (~same occ). A/B/convert byte-identical to r40.

typedef __attribute__((ext_vector_type(8))) short bf16x8;
typedef __attribute__((ext_vector_type(4))) float f32x4;

__device__ __forceinline__ unsigned short bfu(float f) {
  __hip_bfloat16 h = __float2bfloat16(f);
  return *reinterpret_cast<unsigned short*>(&h);
}
__device__ __forceinline__ float b2f(unsigned short u) {
  unsigned x = ((unsigned)u) << 16;
  return __uint_as_float(x);
}
__device__ __forceinline__ float fast_sigmoid(float x) {
  return __builtin_amdgcn_rcpf(1.0f + __expf(-x));
}

// ---------------------------------------------------------------------------
// Kernel A: per-(center, chunk) partial top-16, d2-deferred, 4x-unrolled
// ---------------------------------------------------------------------------
__global__ __launch_bounds__(TPB) void knn_partial_kernel(
    const float* __restrict__ points, const int* __restrict__ cidx,
    float* __restrict__ pvals, int* __restrict__ pidx)
{
#pragma clang fp contract(off)
  const int s  = blockIdx.x;
  const int mg = blockIdx.y;
  const int b  = blockIdx.z;
  const int tid = threadIdx.x;

  __shared__ float4 pts[CHUNK];
  __shared__ unsigned long long buf[12][TPB];

  const int j0 = s * CHUNK;
  for (int e = tid; e < CHUNK; e += TPB) {
    int j = j0 + e;
    float x = points[(b * N_ + j) * 3 + 0];
    float y = points[(b * N_ + j) * 3 + 1];
    float z = points[(b * N_ + j) * 3 + 2];
    float bq = (x * x + z * z) + y * y;      // einsum SSE2 tree
    pts[e] = make_float4(x, y, z, bq);
  }

  const int m  = mg * TPB + tid;
  const int cm = b * M_ + m;
  const int ci = cidx[cm];
  const float cx = points[(b * N_ + ci) * 3 + 0];
  const float cy = points[(b * N_ + ci) * 3 + 1];
  const float cz = points[(b * N_ + ci) * 3 + 2];
  const float aq = (cx * cx + cz * cz) + cy * cy;   // einsum SSE2 tree
  __syncthreads();

  float v[16];
  int   id[16];
#pragma unroll
  for (int t = 0; t < 16; t++) { v[t] = 3.4e38f; id[t] = 0; }
  float v15q = 0.0905f;
  int cnt = 0;

  for (int e0 = 0; e0 < CHUNK; e0 += 4) {
#pragma unroll
    for (int u = 0; u < 4; u++) {
      int e = e0 + u;
      float4 p = pts[e];
      float dot = fmaf(cz, p.z, fmaf(cy, p.y, cx * p.x));  // BLAS fma chain
      float d2 = fmaf(-2.0f, dot, aq + p.w);
      if (d2 < v15q) {
        buf[cnt][tid] =
            ((unsigned long long)__float_as_uint(d2) << 32) | (unsigned)(j0 + e);
        cnt++;
      }
    }
    if (__any(cnt >= 8)) {
      for (int ss = 0; ss < 12; ss++) {
        if (ss < cnt) {
          unsigned long long kk = buf[ss][tid];
          float d2v = __uint_as_float((unsigned)(kk >> 32));
          int j = (int)(kk & 0xffffffffULL);
          float d2c = fmaxf(d2v, 0.0f);
          float dist = __fsqrt_rn(d2c + SEPS);
          float md = (dist <= MAX_R) ? dist : BIGF;
          if (md < v[15]) {
            bool cg[16];
#pragma unroll
            for (int t = 0; t < 16; t++) cg[t] = (v[t] > md);
#pragma unroll
            for (int t = 15; t >= 1; t--) {
              v[t]  = cg[t - 1] ? v[t - 1]  : (cg[t] ? md : v[t]);
              id[t] = cg[t - 1] ? id[t - 1] : (cg[t] ? j  : id[t]);
            }
            if (cg[0]) { v[0] = md; id[0] = j; }
          }
        }
      }
      cnt = 0;
      float v15 = v[15];
      v15q = fminf(0.0905f, fmaf(v15, v15, 1e-6f));
    }
  }

  for (int ss = 0; ss < 12; ss++) {
    if (ss < cnt) {
      unsigned long long kk = buf[ss][tid];
      float d2v = __uint_as_float((unsigned)(kk >> 32));
      int j = (int)(kk & 0xffffffffULL);
      float d2c = fmaxf(d2v, 0.0f);
      float dist = __fsqrt_rn(d2c + SEPS);
      float md = (dist <= MAX_R) ? dist : BIGF;
      if (md < v[15]) {
        bool cg[16];
#pragma unroll
        for (int t = 0; t < 16; t++) cg[t] = (v[t] > md);
#pragma unroll
        for (int t = 15; t >= 1; t--) {
          v[t]  = cg[t - 1] ? v[t - 1]  : (cg[t] ? md : v[t]);
          id[t] = cg[t - 1] ? id[t - 1] : (cg[t] ? j  : id[t]);
        }
        if (cg[0]) { v[0] = md; id[0] = j; }
      }
    }
  }

#pragma unroll
  for (int t = 0; t < 16; t++) {
    int o = (s * 16 + t) * BM + cm;
    pvals[o] = v[t];
    pidx[o]  = id[t];
  }
}

// ---------------------------------------------------------------------------
// Kernel B: merge S_CHUNKS sorted partial lists (64 thr/block)  [FROZEN]
// ---------------------------------------------------------------------------
__global__ __launch_bounds__(64) void knn_merge_kernel(
    const float* __restrict__ pvals, const int* __restrict__ pidx,
    int* __restrict__ kidx, float* __restrict__ dout)
{
  const int cm = blockIdx.x * 64 + threadIdx.x;

  unsigned long long key[16];
#pragma unroll
  for (int t = 0; t < 16; t++) {
    int o = t * BM + cm;
    unsigned int vb = __float_as_uint(pvals[o]);
    key[t] = ((unsigned long long)vb << 32) | (unsigned int)pidx[o];
  }
  for (int s = 1; s < S_CHUNKS; s++) {
    for (int t2 = 0; t2 < 16; t2++) {
      int o = (s * 16 + t2) * BM + cm;
      unsigned int vb = __float_as_uint(pvals[o]);
      unsigned long long Kk = ((unsigned long long)vb << 32) | (unsigned int)pidx[o];
      if (Kk >= key[15]) break;
      bool cg[16];
#pragma unroll
      for (int t = 0; t < 16; t++) cg[t] = (key[t] > Kk);
#pragma unroll
      for (int t = 15; t >= 1; t--)
        key[t] = cg[t - 1] ? key[t - 1] : (cg[t] ? Kk : key[t]);
      if (cg[0]) key[0] = Kk;
    }
  }
#pragma unroll
  for (int t = 0; t < 16; t++) {
    int j = (int)(key[t] & 0xffffffffULL);
    kidx[cm * K_ + t] = j;
    dout[(size_t)BM * OUT_ + (size_t)cm * K_ + t] = (float)j;
  }
}

// ---------------------------------------------------------------------------
// Pre-kernel: W1/W2/Wm -> bf16 col-major
// ---------------------------------------------------------------------------
__global__ __launch_bounds__(TPB) void convert_weights_kernel(
    const float* __restrict__ W1, const float* __restrict__ W2,
    const float* __restrict__ Wm,
    unsigned short* __restrict__ Wt1, unsigned short* __restrict__ Wt2,
    unsigned short* __restrict__ Wtm)
{
  int t = blockIdx.x * TPB + threadIdx.x;
  if (t < 128 * 256) {
    int col = t >> 8, k = t & 255;
    Wt1[t] = bfu(W1[k * 128 + col]);
  } else if (t < 128 * 256 + 128 * 128) {
    int u = t - 128 * 256;
    int col = u >> 7, k = u & 127;
    Wt2[u] = bfu(W2[k * 128 + col]);
  } else {
    int w = t - (128 * 256 + 128 * 128);
    int col = w >> 7, k = w & 127;
    Wtm[w] = bfu(Wm[k * 256 + col]);
  }
}

// ---------------------------------------------------------------------------
// Kernel C: 4 centers/block, 512 threads, LDS-aliased, fast transcendentals
// ---------------------------------------------------------------------------
__global__ __launch_bounds__(512, 2) void fuse_mlp_kernel(
    const float* __restrict__ feats, const int* __restrict__ cidx,
    const int* __restrict__ kidx,
    const float* __restrict__ ln1w, const float* __restrict__ ln1b,
    const unsigned short* __restrict__ Wt1, const float* __restrict__ b1,
    const unsigned short* __restrict__ Wt2, const float* __restrict__ b2,
    const unsigned short* __restrict__ Wtm, const float* __restrict__ bm,
    const float* __restrict__ ln2w, const float* __restrict__ ln2b,
    const float* __restrict__ res_scale,
    float* __restrict__ dout)
{
  const int cm0 = blockIdx.x * 4;          // M_ % 4 == 0 => same batch
  const int b   = cm0 >> 12;
  const int tid = threadIdx.x;
  const int lane = tid & 63, wv = tid >> 6;   // wv in 0..7

  __shared__ float cf[4][C_];
  __shared__ __align__(16) unsigned short nb[4][K_][136];
  __shared__ __align__(16) char pool[4 * K_ * 272 * 2];   // cn | (hb,wbb)
  __shared__ __align__(16) unsigned short fvb[4][136];
  __shared__ float outb[4][OUT_];
  __shared__ float red[2][4];
  __shared__ int nidx[4][K_];

  typedef unsigned short cn_t[K_][272];
  typedef unsigned short hw_t[K_][136];
  cn_t* cn  = (cn_t*)pool;                          // [4][16][272] = 34816 B
  hw_t* hb  = (hw_t*)pool;                          // [4][16][136] = 17408 B
  hw_t* wbb = (hw_t*)(pool + 4 * K_ * 136 * 2);     // next 17408 B

  if (tid < 64) {
    int c = tid >> 4, t = tid & 15;
    nidx[c][t] = kidx[(cm0 + c) * K_ + t];
  }
  __syncthreads();

  // gather: 4 centers x (1 cf row + 16 neigh rows) x 32 float4 = 2176 items
  for (int t = tid; t < 2176; t += 512) {
    int c = t / 544;
    int u = t - c * 544;
    int row = u >> 5, c4 = u & 31;
    int src = (row == 0) ? cidx[cm0 + c] : nidx[c][row - 1];
    float4 val = *(const float4*)&feats[((size_t)b * N_ + src) * C_ + c4 * 4];
    if (row == 0) {
      *(float4*)&cf[c][c4 * 4] = val;
    } else {
      int r = row - 1, cc = c4 * 4;
      nb[c][r][cc]     = bfu(val.x);
      nb[c][r][cc + 1] = bfu(val.y);
      nb[c][r][cc + 2] = bfu(val.z);
      nb[c][r][cc + 3] = bfu(val.w);
    }
  }
  __syncthreads();

  // LN1: wave wv handles k = wv*2 + kk (8 waves x 2 = 16 k), all 4 centers
  for (int kk = 0; kk < 2; kk++) {
    int k = wv * 2 + kk;
#pragma unroll
    for (int c = 0; c < 4; c++) {
      float x0 = cf[c][lane];
      float x1 = cf[c][lane + 64];
      float x2 = b2f(nb[c][k][lane]);
      float x3 = b2f(nb[c][k][lane + 64]);
      float ssum = ((x0 + x1) + (x2 + x3));
#pragma unroll
      for (int off = 1; off < 64; off <<= 1) ssum += __shfl_xor(ssum, off, 64);
      float mu = ssum * (1.0f / 256.0f);
      float d0 = x0 - mu, d1 = x1 - mu, d2 = x2 - mu, d3 = x3 - mu;
      float vs = fmaf(d0, d0, fmaf(d1, d1, fmaf(d2, d2, d3 * d3)));
#pragma unroll
      for (int off = 1; off < 64; off <<= 1) vs += __shfl_xor(vs, off, 64);
      float var = vs * (1.0f / 256.0f);
      float rs = __builtin_amdgcn_rsqf(var + LN_EPS_F);
      cn[c][k][lane]       = bfu(fmaf(d0 * rs, ln1w[lane],       ln1b[lane]));
      cn[c][k][lane + 64]  = bfu(fmaf(d1 * rs, ln1w[lane + 64],  ln1b[lane + 64]));
      cn[c][k][lane + 128] = bfu(fmaf(d2 * rs, ln1w[lane + 128], ln1b[lane + 128]));
      cn[c][k][lane + 192] = bfu(fmaf(d3 * rs, ln1w[lane + 192], ln1b[lane + 192]));
    }
  }
  __syncthreads();

  const int r16 = lane & 15;
  const int kg  = lane >> 4;
  const int col1 = wv * 16 + r16;   // wave's GEMM1/2 column (N=128, 8 ntiles)

  // GEMM1: one B-frag load feeds 4 centers' MFMAs
  f32x4 a[4] = {{0.f,0.f,0.f,0.f},{0.f,0.f,0.f,0.f},{0.f,0.f,0.f,0.f},{0.f,0.f,0.f,0.f}};
#pragma unroll
  for (int kt = 0; kt < 8; kt++) {
    int k0 = kt * 32 + kg * 8;
    bf16x8 g = *(const bf16x8*)&Wt1[(size_t)col1 * 256 + k0];
#pragma unroll
    for (int c = 0; c < 4; c++) {
      bf16x8 af = *(const bf16x8*)&cn[c][r16][k0];
      a[c] = __builtin_amdgcn_mfma_f32_16x16x32_bf16(af, g, a[c], 0, 0, 0);
    }
  }
  __syncthreads();   // cn reads complete before hb overwrites the pool
#pragma unroll
  for (int c = 0; c < 4; c++)
#pragma unroll
    for (int r = 0; r < 4; r++) {
      int ro = kg * 4 + r;
      hb[c][ro][col1] = bfu(fmaxf(a[c][r] + b1[col1], 0.f));
    }
  __syncthreads();

  // GEMM2
  f32x4 s[4] = {{0.f,0.f,0.f,0.f},{0.f,0.f,0.f,0.f},{0.f,0.f,0.f,0.f},{0.f,0.f,0.f,0.f}};
#pragma unroll
  for (int kt = 0; kt < 4; kt++) {
    int k0 = kt * 32 + kg * 8;
    bf16x8 g = *(const bf16x8*)&Wt2[(size_t)col1 * 128 + k0];
#pragma unroll
    for (int c = 0; c < 4; c++) {
      bf16x8 af = *(const bf16x8*)&hb[c][r16][k0];
      s[c] = __builtin_amdgcn_mfma_f32_16x16x32_bf16(af, g, s[c], 0, 0, 0);
    }
  }
#pragma unroll
  for (int c = 0; c < 4; c++)
#pragma unroll
    for (int r = 0; r < 4; r++) {
      int ro = kg * 4 + r;
      wbb[c][ro][col1] = bfu(fast_sigmoid(s[c][r] + b2[col1]));
    }
  __syncthreads();

  // weighted mean + residual fuse: 512 threads = 4 centers x 128 cols
  {
    int c = tid >> 7, col = tid & 127;
    float ssum = 0.f;
#pragma unroll
    for (int kq = 0; kq < 16; kq++)
      ssum = fmaf(b2f(nb[c][kq][col]), b2f(wbb[c][kq][col]), ssum);
    float wmean = ssum * (1.0f / 16.0f);
    fvb[c][col] = bfu(fmaf(res_scale[0], wmean, cf[c][col]));
  }
  __syncthreads();

  // GEMM3 (row-replicated A): 16 ntiles over 8 waves = 2/wave, 4 centers each
#pragma unroll
  for (int i = 0; i < 2; i++) {
    int cb = (wv * 2 + i) * 16;
    f32x4 acc[4] = {{0.f,0.f,0.f,0.f},{0.f,0.f,0.f,0.f},{0.f,0.f,0.f,0.f},{0.f,0.f,0.f,0.f}};
#pragma unroll
    for (int kt = 0; kt < 4; kt++) {
      int k0 = kt * 32 + kg * 8;
      bf16x8 gf = *(const bf16x8*)&Wtm[(size_t)(cb + r16) * 128 + k0];
#pragma unroll
      for (int c = 0; c < 4; c++) {
        bf16x8 af = *(const bf16x8*)&fvb[c][k0];
        acc[c] = __builtin_amdgcn_mfma_f32_16x16x32_bf16(af, gf, acc[c], 0, 0, 0);
      }
    }
    if (kg == 0) {
      int cc = cb + r16;
#pragma unroll
      for (int c = 0; c < 4; c++)
        outb[c][cc] = fmaxf(acc[c][0] + bm[cc], 0.f);
    }
  }
  __syncthreads();

  // LN2: 4 centers x 256 cols over 512 threads, 2 passes
  {
    int grp = tid >> 8;            // 0..1
    int col = tid & 255;
    int wvin = (tid >> 6) & 3;     // wave within group
    for (int cpass = 0; cpass < 2; cpass++) {
      int c = cpass * 2 + grp;
      float outx = outb[c][col];
      float su = outx;
#pragma unroll
      for (int off = 1; off < 64; off <<= 1) su += __shfl_xor(su, off, 64);
      if (lane == 0) red[grp][wvin] = su;
      __syncthreads();
      float mu = (red[grp][0] + red[grp][1] + red[grp][2] + red[grp][3]) * (1.0f / 256.0f);
      float d = outx - mu;
      float s2 = d * d;
#pragma unroll
      for (int off = 1; off < 64; off <<= 1) s2 += __shfl_xor(s2, off, 64);
      __syncthreads();
      if (lane == 0) red[grp][wvin] = s2;
      __syncthreads();
      float var = (red[grp][0] + red[grp][1] + red[grp][2] + red[grp][3]) * (1.0f / 256.0f);
      float rs2 = __builtin_amdgcn_rsqf(var + LN_EPS_F);
      dout[(size_t)(cm0 + c) * OUT_ + col] = fmaf(d * rs2, ln2w[col], ln2b[col]);
      __syncthreads();
    }
  }
}

// ---------------------------------------------------------------------------
extern "C" void kernel_launch(void* const* d_in, const int* in_sizes, int n_in,
                              void* d_out, int out_size, void* d_ws, size_t ws_size,
                              hipStream_t stream) {
  const float* points = (const float*)d_in[0];
  const float* feats  = (const float*)d_in[1];
  const int*   cidx   = (const int*)  d_in[2];
  const float* ln1w   = (const float*)d_in[3];
  const float* ln1b   = (const float*)d_in[4];
  const float* W1     = (const float*)d_in[5];
  const float* b1     = (const float*)d_in[6];
  const float* W2     = (const float*)d_in[7];
  const float* b2     = (const float*)d_in[8];
  const float* Wm     = (const float*)d_in[9];
  const float* bm     = (const float*)d_in[10];
  const float* ln2w   = (const float*)d_in[11];
  const float* ln2b   = (const float*)d_in[12];
  const float* rscale = (const float*)d_in[13];

  float* out = (float*)d_out;
  char*  ws  = (char*)d_ws;
  float* pvals = (float*)ws;
  int*   pidx  = (int*)(ws + 16777216);
  int*   kidx  = (int*)(ws + 33554432);
  unsigned short* Wt1 = (unsigned short*)(ws + 34603008);
  unsigned short* Wt2 = (unsigned short*)(ws + 34603008 + 65536);
  unsigned short* Wtm = (unsigned short*)(ws + 34603008 + 65536 + 32768);

  convert_weights_kernel<<<(128 * 256 + 128 * 128 + 256 * 128 + TPB - 1) / TPB,
                           TPB, 0, stream>>>(W1, W2, Wm, Wt1, Wt2, Wtm);
  knn_partial_kernel<<<dim3(S_CHUNKS, M_ / TPB, B_), TPB, 0, stream>>>(points, cidx, pvals, pidx);
  knn_merge_kernel<<<BM / 64, 64, 0, stream>>>(pvals, pidx, kidx, out);
  fuse_mlp_kernel<<<BM / 4, 512, 0, stream>>>(feats, cidx, kidx,
                                              ln1w, ln1b, Wt1, b1, Wt2, b2, Wtm, bm,
                                              ln2w, ln2b, rscale, out);
}